// Round 1
// baseline (1295.059 us; speedup 1.0000x reference)
//
#include <hip/hip_runtime.h>
#include <math.h>

#define NN 100000
#define IN_DIM 256
#define HCH 128      // HEADS*HID
#define OUT_DIM 64
#define EE 1600000
#define NEG_SLOPE 0.2f

__device__ __forceinline__ float lrelu(float v) { return v > 0.f ? v : NEG_SLOPE * v; }

// ---------------- GEMM: h[n][128] = x[n][256] @ W[256][128] ----------------
// block 256 thr, tile 64 nodes x 128 cols, K-tile 16
__global__ __launch_bounds__(256) void gemm_kernel(const float* __restrict__ x,
                                                   const float* __restrict__ W,
                                                   float* __restrict__ h, int n)
{
    __shared__ float xs[64][16];
    __shared__ float ws[16][128];
    const int tid = threadIdx.x;
    const int cg = tid & 31;   // 4 cols each
    const int ng = tid >> 5;   // 8 nodes each
    const int nt0 = blockIdx.x * 64;

    float acc[8][4];
#pragma unroll
    for (int i = 0; i < 8; ++i)
#pragma unroll
        for (int j = 0; j < 4; ++j) acc[i][j] = 0.f;

    for (int kt = 0; kt < IN_DIM; kt += 16) {
        // stage x tile: 64x16 floats, one float4/thread
        {
            int node = nt0 + (tid >> 2);
            int kk = (tid & 3) * 4;
            float4 v = make_float4(0.f, 0.f, 0.f, 0.f);
            if (node < n) v = *(const float4*)(x + (size_t)node * IN_DIM + kt + kk);
            *(float4*)&xs[tid >> 2][kk] = v;
        }
        // stage W tile: 16x128 floats, two float4/thread
#pragma unroll
        for (int r = 0; r < 2; ++r) {
            int f = (r * 256 + tid) * 4;
            int k = f >> 7, c = f & 127;
            *(float4*)&ws[k][c] = *(const float4*)(W + (size_t)(kt + k) * HCH + c);
        }
        __syncthreads();
#pragma unroll
        for (int k = 0; k < 16; ++k) {
            float4 w4 = *(float4*)&ws[k][cg * 4];
#pragma unroll
            for (int i = 0; i < 8; ++i) {
                float a = xs[ng * 8 + i][k];
                acc[i][0] = fmaf(a, w4.x, acc[i][0]);
                acc[i][1] = fmaf(a, w4.y, acc[i][1]);
                acc[i][2] = fmaf(a, w4.z, acc[i][2]);
                acc[i][3] = fmaf(a, w4.w, acc[i][3]);
            }
        }
        __syncthreads();
    }
#pragma unroll
    for (int i = 0; i < 8; ++i) {
        int node = nt0 + ng * 8 + i;
        if (node < n)
            *(float4*)(h + (size_t)node * HCH + cg * 4) =
                make_float4(acc[i][0], acc[i][1], acc[i][2], acc[i][3]);
    }
}

// ---------------- attention scores a_s/a_d [N][2] ----------------
// wave per node
__global__ __launch_bounds__(256) void att_kernel(const float* __restrict__ h,
                                                  const float* __restrict__ att_src,
                                                  const float* __restrict__ att_dst,
                                                  float2* __restrict__ a_s,
                                                  float2* __restrict__ a_d, int n)
{
    int wid = threadIdx.x >> 6, lane = threadIdx.x & 63;
    int node = blockIdx.x * 4 + wid;
    if (node >= n) return;
    float2 hv = *(const float2*)(h + (size_t)node * HCH + 2 * lane);
    int c0 = 2 * lane;  // == head*64 + c
    float ps = hv.x * att_src[c0] + hv.y * att_src[c0 + 1];
    float pd = hv.x * att_dst[c0] + hv.y * att_dst[c0 + 1];
#pragma unroll
    for (int m = 16; m >= 1; m >>= 1) {
        ps += __shfl_xor(ps, m, 64);
        pd += __shfl_xor(pd, m, 64);
    }
    float ps1 = __shfl(ps, 32, 64);
    float pd1 = __shfl(pd, 32, 64);
    if (lane == 0) {
        a_s[node] = make_float2(ps, ps1);
        a_d[node] = make_float2(pd, pd1);
    }
}

// ---------------- CSR build ----------------
__global__ void hist_kernel(const int* __restrict__ dst, int* __restrict__ counts, int e)
{
    int i = blockIdx.x * blockDim.x + threadIdx.x;
    if (i < e) atomicAdd(&counts[dst[i]], 1);
}

__global__ __launch_bounds__(256) void scan1_kernel(const int* __restrict__ counts,
                                                    int* __restrict__ indptr,
                                                    int* __restrict__ bsums, int n)
{
    __shared__ int sd[256];
    int tid = threadIdx.x;
    int i0 = blockIdx.x * 1024 + tid * 4;
    int c[4];
#pragma unroll
    for (int j = 0; j < 4; ++j) c[j] = (i0 + j < n) ? counts[i0 + j] : 0;
    int ts = c[0] + c[1] + c[2] + c[3];
    sd[tid] = ts;
    __syncthreads();
    int v = ts;
    for (int off = 1; off < 256; off <<= 1) {
        int t = (tid >= off) ? sd[tid - off] : 0;
        __syncthreads();
        v += t;
        sd[tid] = v;
        __syncthreads();
    }
    int e0 = v - ts;  // exclusive within block
#pragma unroll
    for (int j = 0; j < 4; ++j) {
        if (i0 + j < n) indptr[i0 + j] = e0;
        e0 += c[j];
    }
    if (tid == 255) bsums[blockIdx.x] = sd[255];
}

__global__ __launch_bounds__(128) void scan2_kernel(int* bsums, int nb)
{
    __shared__ int sd[128];
    int tid = threadIdx.x;
    int v0 = (tid < nb) ? bsums[tid] : 0;
    sd[tid] = v0;
    __syncthreads();
    int v = v0;
    for (int off = 1; off < 128; off <<= 1) {
        int t = (tid >= off) ? sd[tid - off] : 0;
        __syncthreads();
        v += t;
        sd[tid] = v;
        __syncthreads();
    }
    if (tid < nb) bsums[tid] = v - v0;  // exclusive
}

__global__ void scan3_kernel(int* __restrict__ indptr, int* __restrict__ cursor,
                             const int* __restrict__ bsums, int n, int etot)
{
    int i = blockIdx.x * blockDim.x + threadIdx.x;
    if (i < n) {
        int v = indptr[i] + bsums[i >> 10];
        indptr[i] = v;
        cursor[i] = v;
    } else if (i == n) {
        indptr[n] = etot;
    }
}

__global__ void scatter_kernel(const int* __restrict__ src, const int* __restrict__ dst,
                               int* __restrict__ cursor, int* __restrict__ ssrc, int e)
{
    int i = blockIdx.x * blockDim.x + threadIdx.x;
    if (i < e) {
        int pos = atomicAdd(&cursor[dst[i]], 1);
        ssrc[pos] = src[i];
    }
}

// ---------------- per-node softmax aggregation + fused FC ----------------
// wave per dst node; 4 waves/block
__global__ __launch_bounds__(256) void agg_kernel(
    const float* __restrict__ h, const float2* __restrict__ a_s,
    const float2* __restrict__ a_d, const int* __restrict__ indptr,
    const int* __restrict__ ssrc, const float* __restrict__ bias,
    const float* __restrict__ fcW, const float* __restrict__ fcb,
    float* __restrict__ out, int n, int layer)
{
    __shared__ float xb[4][HCH];
    int wid = threadIdx.x >> 6, lane = threadIdx.x & 63;
    int node = blockIdx.x * 4 + wid;
    bool valid = node < n;
    int nn = valid ? node : 0;
    int start = indptr[nn], end = indptr[nn + 1];
    float2 ad = a_d[nn];
    float2 asn = a_s[nn];

    // pass 1: per-head max (edge-parallel + butterfly)
    float mx0 = -3.4e38f, mx1 = -3.4e38f;
    for (int j = start + lane; j < end; j += 64) {
        int s = ssrc[j];
        float2 a = a_s[s];
        mx0 = fmaxf(mx0, lrelu(a.x + ad.x));
        mx1 = fmaxf(mx1, lrelu(a.y + ad.y));
    }
#pragma unroll
    for (int m = 32; m >= 1; m >>= 1) {
        mx0 = fmaxf(mx0, __shfl_xor(mx0, m, 64));
        mx1 = fmaxf(mx1, __shfl_xor(mx1, m, 64));
    }
    float es0 = lrelu(asn.x + ad.x), es1 = lrelu(asn.y + ad.y);
    mx0 = fmaxf(mx0, es0);
    mx1 = fmaxf(mx1, es1);

    // pass 2: channel-parallel accumulate p*h and denom (normalize after)
    float acc0 = 0.f, acc1 = 0.f, s0 = 0.f, s1 = 0.f;
    for (int j = start; j < end; ++j) {
        int s = ssrc[j];
        float2 a = a_s[s];
        float p0 = __expf(lrelu(a.x + ad.x) - mx0);
        float p1 = __expf(lrelu(a.y + ad.y) - mx1);
        float2 hv = *(const float2*)(h + (size_t)s * HCH + 2 * lane);
        float pl = (lane < 32) ? p0 : p1;
        acc0 += pl * hv.x;
        acc1 += pl * hv.y;
        s0 += p0;
        s1 += p1;
    }
    {   // self loop
        float p0 = __expf(es0 - mx0), p1 = __expf(es1 - mx1);
        float2 hv = *(const float2*)(h + (size_t)nn * HCH + 2 * lane);
        float pl = (lane < 32) ? p0 : p1;
        acc0 += pl * hv.x;
        acc1 += pl * hv.y;
        s0 += p0;
        s1 += p1;
    }
    float sl = (lane < 32) ? s0 : s1;
    float o0 = fmaxf(acc0 / sl + bias[2 * lane], 0.f);
    float o1 = fmaxf(acc1 / sl + bias[2 * lane + 1], 0.f);
    xb[wid][2 * lane] = o0;
    xb[wid][2 * lane + 1] = o1;
    __syncthreads();

    // fused FC half: out[n][lane] (+)= sum_k xb[k] * fcW[layer*128 + k][lane]
    float sum = (layer == 0) ? fcb[lane] : out[(size_t)nn * OUT_DIM + lane];
    const float* fw = fcW + (size_t)layer * HCH * OUT_DIM + lane;
    const float* xrow = xb[wid];
#pragma unroll 8
    for (int k = 0; k < HCH; ++k) sum += xrow[k] * fw[(size_t)k * OUT_DIM];
    if (valid) out[(size_t)node * OUT_DIM + lane] = sum;
}

// ---------------- launch ----------------
extern "C" void kernel_launch(void* const* d_in, const int* in_sizes, int n_in,
                              void* d_out, int out_size, void* d_ws, size_t ws_size,
                              hipStream_t stream)
{
    const float* x = (const float*)d_in[0];
    const int* ei[2] = { (const int*)d_in[1], (const int*)d_in[2] };
    const float* W[2] = { (const float*)d_in[3], (const float*)d_in[7] };
    const float* attS[2] = { (const float*)d_in[4], (const float*)d_in[8] };
    const float* attD[2] = { (const float*)d_in[5], (const float*)d_in[9] };
    const float* bias[2] = { (const float*)d_in[6], (const float*)d_in[10] };
    const float* fcW = (const float*)d_in[11];
    const float* fcb = (const float*)d_in[12];
    float* out = (float*)d_out;

    // workspace carve (256B aligned)
    char* p = (char*)d_ws;
    size_t need = 0;
    auto carve = [&](size_t bytes) {
        char* r = p;
        size_t b = (bytes + 255) & ~(size_t)255;
        p += b;
        need += b;
        return r;
    };
    float* h = (float*)carve((size_t)NN * HCH * 4);
    float2* a_s = (float2*)carve((size_t)NN * 8);
    float2* a_d = (float2*)carve((size_t)NN * 8);
    int* counts = (int*)carve((size_t)NN * 4);
    int* indptr = (int*)carve((size_t)(NN + 1) * 4);
    int* cursor = (int*)carve((size_t)NN * 4);
    int* bsums = (int*)carve(1024);
    int* ssrc = (int*)carve((size_t)EE * 4);
    if (need > ws_size) return;  // loud correctness failure instead of OOB crash

    const int gemm_blocks = (NN + 63) / 64;        // 1563
    const int node_blocks = (NN + 3) / 4;          // 25000
    const int edge_blocks = (EE + 255) / 256;      // 6250
    const int scan_blocks = (NN + 1023) / 1024;    // 98
    const int scan3_blocks = (NN + 1 + 255) / 256; // 391

    for (int layer = 0; layer < 2; ++layer) {
        gemm_kernel<<<gemm_blocks, 256, 0, stream>>>(x, W[layer], h, NN);
        att_kernel<<<node_blocks, 256, 0, stream>>>(h, attS[layer], attD[layer], a_s, a_d, NN);
        hipMemsetAsync(counts, 0, (size_t)NN * 4, stream);
        hist_kernel<<<edge_blocks, 256, 0, stream>>>(ei[layer] + EE, counts, EE);
        scan1_kernel<<<scan_blocks, 256, 0, stream>>>(counts, indptr, bsums, NN);
        scan2_kernel<<<1, 128, 0, stream>>>(bsums, scan_blocks);
        scan3_kernel<<<scan3_blocks, 256, 0, stream>>>(indptr, cursor, bsums, NN, EE);
        scatter_kernel<<<edge_blocks, 256, 0, stream>>>(ei[layer], ei[layer] + EE, cursor, ssrc, EE);
        agg_kernel<<<node_blocks, 256, 0, stream>>>(h, a_s, a_d, indptr, ssrc,
                                                    bias[layer], fcW, fcb, out, NN, layer);
    }
}

// Round 2
// 1090.716 us; speedup vs baseline: 1.1873x; 1.1873x over previous
//
#include <hip/hip_runtime.h>
#include <math.h>

#define NN 100000
#define IN_DIM 256
#define HCH 128      // HEADS*HID
#define OUT_DIM 64
#define EE 1600000
#define NEG_SLOPE 0.2f

__device__ __forceinline__ float lrelu(float v) { return v > 0.f ? v : NEG_SLOPE * v; }

// ---------------- GEMM: h[n][128] = x[n][256] @ W[256][128] ----------------
// 128x128 tile, 256 thr, 8x8 micro-tile per thread, K-tile 16
__global__ __launch_bounds__(256) void gemm_kernel(const float* __restrict__ x,
                                                   const float* __restrict__ W,
                                                   float* __restrict__ h, int n)
{
    __shared__ float xs[16][132];   // k-major, padded
    __shared__ float ws[16][128];
    const int tid = threadIdx.x;
    const int tx = tid & 15;        // cols tx*8 .. +7
    const int ty = tid >> 4;        // rows ty*8 .. +7
    const int row0 = blockIdx.x * 128;

    float acc[8][8];
#pragma unroll
    for (int i = 0; i < 8; ++i)
#pragma unroll
        for (int j = 0; j < 8; ++j) acc[i][j] = 0.f;

    for (int kt = 0; kt < IN_DIM; kt += 16) {
        // stage x tile (transposed to k-major): 128 rows x 16 k
        {
            const int r = tid >> 2;
            const int kg = (tid & 3) * 4;
#pragma unroll
            for (int half = 0; half < 2; ++half) {
                const int row = r + half * 64;
                float4 v = make_float4(0.f, 0.f, 0.f, 0.f);
                if (row0 + row < n)
                    v = *(const float4*)(x + (size_t)(row0 + row) * IN_DIM + kt + kg);
                xs[kg + 0][row] = v.x;
                xs[kg + 1][row] = v.y;
                xs[kg + 2][row] = v.z;
                xs[kg + 3][row] = v.w;
            }
        }
        // stage W tile: 16 x 128
#pragma unroll
        for (int r = 0; r < 2; ++r) {
            const int idx = r * 256 + tid;   // 0..511 float4s
            const int k = idx >> 5;
            const int c = (idx & 31) * 4;
            *(float4*)&ws[k][c] = *(const float4*)(W + (size_t)(kt + k) * HCH + c);
        }
        __syncthreads();
#pragma unroll
        for (int k = 0; k < 16; ++k) {
            const float4 a0 = *(float4*)&xs[k][ty * 8];
            const float4 a1 = *(float4*)&xs[k][ty * 8 + 4];
            const float4 b0 = *(float4*)&ws[k][tx * 8];
            const float4 b1 = *(float4*)&ws[k][tx * 8 + 4];
            const float av[8] = { a0.x, a0.y, a0.z, a0.w, a1.x, a1.y, a1.z, a1.w };
            const float bv[8] = { b0.x, b0.y, b0.z, b0.w, b1.x, b1.y, b1.z, b1.w };
#pragma unroll
            for (int i = 0; i < 8; ++i)
#pragma unroll
                for (int j = 0; j < 8; ++j)
                    acc[i][j] = fmaf(av[i], bv[j], acc[i][j]);
        }
        __syncthreads();
    }
#pragma unroll
    for (int i = 0; i < 8; ++i) {
        const int row = row0 + ty * 8 + i;
        if (row < n) {
            *(float4*)(h + (size_t)row * HCH + tx * 8) =
                make_float4(acc[i][0], acc[i][1], acc[i][2], acc[i][3]);
            *(float4*)(h + (size_t)row * HCH + tx * 8 + 4) =
                make_float4(acc[i][4], acc[i][5], acc[i][6], acc[i][7]);
        }
    }
}

// ---------------- attention scores a_s/a_d [N] float2 ----------------
__global__ __launch_bounds__(256) void att_kernel(const float* __restrict__ h,
                                                  const float* __restrict__ att_src,
                                                  const float* __restrict__ att_dst,
                                                  float2* __restrict__ a_s,
                                                  float2* __restrict__ a_d, int n)
{
    int wid = threadIdx.x >> 6, lane = threadIdx.x & 63;
    int node = blockIdx.x * 4 + wid;
    if (node >= n) return;
    float2 hv = *(const float2*)(h + (size_t)node * HCH + 2 * lane);
    int c0 = 2 * lane;
    float ps = hv.x * att_src[c0] + hv.y * att_src[c0 + 1];
    float pd = hv.x * att_dst[c0] + hv.y * att_dst[c0 + 1];
#pragma unroll
    for (int m = 16; m >= 1; m >>= 1) {
        ps += __shfl_xor(ps, m, 64);
        pd += __shfl_xor(pd, m, 64);
    }
    float ps1 = __shfl(ps, 32, 64);
    float pd1 = __shfl(pd, 32, 64);
    if (lane == 0) {
        a_s[node] = make_float2(ps, ps1);
        a_d[node] = make_float2(pd, pd1);
    }
}

// ---------------- CSR build ----------------
__global__ void hist_kernel(const int* __restrict__ dst, int* __restrict__ counts, int e)
{
    int i = blockIdx.x * blockDim.x + threadIdx.x;
    if (i < e) atomicAdd(&counts[dst[i]], 1);
}

__global__ __launch_bounds__(256) void scan1_kernel(const int* __restrict__ counts,
                                                    int* __restrict__ indptr,
                                                    int* __restrict__ bsums, int n)
{
    __shared__ int sd[256];
    int tid = threadIdx.x;
    int i0 = blockIdx.x * 1024 + tid * 4;
    int c[4];
#pragma unroll
    for (int j = 0; j < 4; ++j) c[j] = (i0 + j < n) ? counts[i0 + j] : 0;
    int ts = c[0] + c[1] + c[2] + c[3];
    sd[tid] = ts;
    __syncthreads();
    int v = ts;
    for (int off = 1; off < 256; off <<= 1) {
        int t = (tid >= off) ? sd[tid - off] : 0;
        __syncthreads();
        v += t;
        sd[tid] = v;
        __syncthreads();
    }
    int e0 = v - ts;
#pragma unroll
    for (int j = 0; j < 4; ++j) {
        if (i0 + j < n) indptr[i0 + j] = e0;
        e0 += c[j];
    }
    if (tid == 255) bsums[blockIdx.x] = sd[255];
}

__global__ __launch_bounds__(128) void scan2_kernel(int* bsums, int nb)
{
    __shared__ int sd[128];
    int tid = threadIdx.x;
    int v0 = (tid < nb) ? bsums[tid] : 0;
    sd[tid] = v0;
    __syncthreads();
    int v = v0;
    for (int off = 1; off < 128; off <<= 1) {
        int t = (tid >= off) ? sd[tid - off] : 0;
        __syncthreads();
        v += t;
        sd[tid] = v;
        __syncthreads();
    }
    if (tid < nb) bsums[tid] = v - v0;
}

__global__ void scan3_kernel(int* __restrict__ indptr, int* __restrict__ cursor,
                             const int* __restrict__ bsums, int n, int etot)
{
    int i = blockIdx.x * blockDim.x + threadIdx.x;
    if (i < n) {
        int v = indptr[i] + bsums[i >> 10];
        indptr[i] = v;
        cursor[i] = v;
    } else if (i == n) {
        indptr[n] = etot;
    }
}

__global__ void scatter_kernel(const int* __restrict__ src, const int* __restrict__ dst,
                               int* __restrict__ cursor, int* __restrict__ ssrc, int e)
{
    int i = blockIdx.x * blockDim.x + threadIdx.x;
    if (i < e) {
        int pos = atomicAdd(&cursor[dst[i]], 1);
        ssrc[pos] = src[i];
    }
}

// ---------------- per-node softmax aggregation (no max pass) ----------------
// wave per dst node; cooperative 64-edge chunks staged in wave-private LDS
__global__ __launch_bounds__(256) void agg_kernel(
    const float* __restrict__ h, const float2* __restrict__ a_s,
    const float2* __restrict__ a_d, const int* __restrict__ indptr,
    const int* __restrict__ ssrc, const float* __restrict__ bias,
    float* __restrict__ xc, int n)
{
    __shared__ float4 sh[4][64];
    const int wid = threadIdx.x >> 6, lane = threadIdx.x & 63;
    const int node = blockIdx.x * 4 + wid;
    const bool valid = node < n;
    const int nn = valid ? node : 0;
    const int start = indptr[nn], end = indptr[nn + 1];
    const float2 ad = a_d[nn];
    const float2 asn = a_s[nn];

    float acc0 = 0.f, acc1 = 0.f;   // channel accumulators (2 ch / lane)
    float s0 = 0.f, s1 = 0.f;       // per-lane partial denominators

    for (int base = start; base < end; base += 64) {
        const int j = base + lane;
        const int cnt = min(64, end - base);
        float p0 = 0.f, p1 = 0.f;
        int s = 0;
        if (j < end) {
            s = ssrc[j];
            float2 a = a_s[s];
            p0 = __expf(lrelu(a.x + ad.x));
            p1 = __expf(lrelu(a.y + ad.y));
        }
        s0 += p0;
        s1 += p1;
        sh[wid][lane] = make_float4(__int_as_float(s), p0, p1, 0.f);
        __builtin_amdgcn_wave_barrier();   // wave-private LDS; DS ops complete in order
        for (int t = 0; t < cnt; ++t) {
            const float4 e = sh[wid][t];
            const float2 hv =
                *(const float2*)(h + (size_t)__float_as_int(e.x) * HCH + 2 * lane);
            const float pl = (lane < 32) ? e.y : e.z;
            acc0 = fmaf(pl, hv.x, acc0);
            acc1 = fmaf(pl, hv.y, acc1);
        }
        __builtin_amdgcn_wave_barrier();
    }
    // self loop
    {
        const float ps0 = __expf(lrelu(asn.x + ad.x));
        const float ps1 = __expf(lrelu(asn.y + ad.y));
        const float2 hv = *(const float2*)(h + (size_t)nn * HCH + 2 * lane);
        const float pl = (lane < 32) ? ps0 : ps1;
        acc0 = fmaf(pl, hv.x, acc0);
        acc1 = fmaf(pl, hv.y, acc1);
        if (lane == 0) { s0 += ps0; s1 += ps1; }
    }
#pragma unroll
    for (int m = 32; m >= 1; m >>= 1) {
        s0 += __shfl_xor(s0, m, 64);
        s1 += __shfl_xor(s1, m, 64);
    }
    const float dl = (lane < 32) ? s0 : s1;
    if (valid) {
        const float o0 = fmaxf(acc0 / dl + bias[2 * lane], 0.f);
        const float o1 = fmaxf(acc1 / dl + bias[2 * lane + 1], 0.f);
        *(float2*)(xc + (size_t)node * HCH + 2 * lane) = make_float2(o0, o1);
    }
}

// ---------------- FC half: out (+)= xc[N,128] @ fcW_half[128,64] (+ fcb) ----
// 128x64 tile, 256 thr, 8x4 micro-tile, K-tile 32
__global__ __launch_bounds__(256) void fc_kernel(const float* __restrict__ xc,
                                                 const float* __restrict__ fw,
                                                 const float* __restrict__ fcb,
                                                 float* __restrict__ out, int n, int beta)
{
    __shared__ float xcs[32][132];
    __shared__ float fws[32][64];
    const int tid = threadIdx.x;
    const int tx = tid & 15;   // cols tx*4
    const int ty = tid >> 4;   // rows ty*8
    const int row0 = blockIdx.x * 128;

    float acc[8][4];
#pragma unroll
    for (int i = 0; i < 8; ++i)
#pragma unroll
        for (int j = 0; j < 4; ++j) acc[i][j] = 0.f;

    for (int kt = 0; kt < HCH; kt += 32) {
        // stage xc tile transposed: 128 rows x 32 k = 1024 float4s, 4/thread
#pragma unroll
        for (int i = 0; i < 4; ++i) {
            const int idx = i * 256 + tid;
            const int row = idx >> 3;
            const int kg = (idx & 7) * 4;
            float4 v = make_float4(0.f, 0.f, 0.f, 0.f);
            if (row0 + row < n)
                v = *(const float4*)(xc + (size_t)(row0 + row) * HCH + kt + kg);
            xcs[kg + 0][row] = v.x;
            xcs[kg + 1][row] = v.y;
            xcs[kg + 2][row] = v.z;
            xcs[kg + 3][row] = v.w;
        }
        // stage fw tile: 32 x 64 = 512 float4s, 2/thread
#pragma unroll
        for (int r = 0; r < 2; ++r) {
            const int idx = r * 256 + tid;
            const int k = idx >> 4;
            const int c = (idx & 15) * 4;
            *(float4*)&fws[k][c] = *(const float4*)(fw + (size_t)(kt + k) * OUT_DIM + c);
        }
        __syncthreads();
#pragma unroll
        for (int k = 0; k < 32; ++k) {
            const float4 a0 = *(float4*)&xcs[k][ty * 8];
            const float4 a1 = *(float4*)&xcs[k][ty * 8 + 4];
            const float4 b = *(float4*)&fws[k][tx * 4];
            const float av[8] = { a0.x, a0.y, a0.z, a0.w, a1.x, a1.y, a1.z, a1.w };
            const float bv[4] = { b.x, b.y, b.z, b.w };
#pragma unroll
            for (int i = 0; i < 8; ++i)
#pragma unroll
                for (int j = 0; j < 4; ++j)
                    acc[i][j] = fmaf(av[i], bv[j], acc[i][j]);
        }
        __syncthreads();
    }
    const float4 bb = *(const float4*)(fcb + tx * 4);
#pragma unroll
    for (int i = 0; i < 8; ++i) {
        const int row = row0 + ty * 8 + i;
        if (row < n) {
            float4 v = make_float4(acc[i][0], acc[i][1], acc[i][2], acc[i][3]);
            if (beta) {
                const float4 o = *(const float4*)(out + (size_t)row * OUT_DIM + tx * 4);
                v.x += o.x; v.y += o.y; v.z += o.z; v.w += o.w;
            } else {
                v.x += bb.x; v.y += bb.y; v.z += bb.z; v.w += bb.w;
            }
            *(float4*)(out + (size_t)row * OUT_DIM + tx * 4) = v;
        }
    }
}

// ---------------- launch ----------------
extern "C" void kernel_launch(void* const* d_in, const int* in_sizes, int n_in,
                              void* d_out, int out_size, void* d_ws, size_t ws_size,
                              hipStream_t stream)
{
    const float* x = (const float*)d_in[0];
    const int* ei[2] = { (const int*)d_in[1], (const int*)d_in[2] };
    const float* W[2] = { (const float*)d_in[3], (const float*)d_in[7] };
    const float* attS[2] = { (const float*)d_in[4], (const float*)d_in[8] };
    const float* attD[2] = { (const float*)d_in[5], (const float*)d_in[9] };
    const float* bias[2] = { (const float*)d_in[6], (const float*)d_in[10] };
    const float* fcW = (const float*)d_in[11];
    const float* fcb = (const float*)d_in[12];
    float* out = (float*)d_out;

    char* p = (char*)d_ws;
    size_t need = 0;
    auto carve = [&](size_t bytes) {
        char* r = p;
        size_t b = (bytes + 255) & ~(size_t)255;
        p += b;
        need += b;
        return r;
    };
    float* h = (float*)carve((size_t)NN * HCH * 4);
    float* xc = (float*)carve((size_t)NN * HCH * 4);
    float2* a_s = (float2*)carve((size_t)NN * 8);
    float2* a_d = (float2*)carve((size_t)NN * 8);
    int* counts = (int*)carve((size_t)NN * 4);
    int* indptr = (int*)carve((size_t)(NN + 1) * 4);
    int* cursor = (int*)carve((size_t)NN * 4);
    int* bsums = (int*)carve(1024);
    int* ssrc = (int*)carve((size_t)EE * 4);
    if (need > ws_size) return;  // loud correctness failure instead of OOB crash

    const int gemm_blocks = (NN + 127) / 128;      // 782
    const int node_blocks = (NN + 3) / 4;          // 25000
    const int edge_blocks = (EE + 255) / 256;      // 6250
    const int scan_blocks = (NN + 1023) / 1024;    // 98
    const int scan3_blocks = (NN + 1 + 255) / 256; // 391

    for (int layer = 0; layer < 2; ++layer) {
        gemm_kernel<<<gemm_blocks, 256, 0, stream>>>(x, W[layer], h, NN);
        att_kernel<<<node_blocks, 256, 0, stream>>>(h, attS[layer], attD[layer], a_s, a_d, NN);
        hipMemsetAsync(counts, 0, (size_t)NN * 4, stream);
        hist_kernel<<<edge_blocks, 256, 0, stream>>>(ei[layer] + EE, counts, EE);
        scan1_kernel<<<scan_blocks, 256, 0, stream>>>(counts, indptr, bsums, NN);
        scan2_kernel<<<1, 128, 0, stream>>>(bsums, scan_blocks);
        scan3_kernel<<<scan3_blocks, 256, 0, stream>>>(indptr, cursor, bsums, NN, EE);
        scatter_kernel<<<edge_blocks, 256, 0, stream>>>(ei[layer], ei[layer] + EE, cursor, ssrc, EE);
        agg_kernel<<<node_blocks, 256, 0, stream>>>(h, a_s, a_d, indptr, ssrc, bias[layer], xc, NN);
        fc_kernel<<<gemm_blocks, 256, 0, stream>>>(xc, fcW + (size_t)layer * HCH * OUT_DIM,
                                                   fcb, out, NN, layer);
    }
}

// Round 3
// 877.442 us; speedup vs baseline: 1.4759x; 1.2431x over previous
//
#include <hip/hip_runtime.h>
#include <hip/hip_fp16.h>
#include <math.h>

#define NN 100000
#define IN_DIM 256
#define HCH 128      // HEADS*HID
#define OUT_DIM 64
#define EE 1600000
#define NEG_SLOPE 0.2f

typedef _Float16 half8v __attribute__((ext_vector_type(8)));
typedef _Float16 half4v __attribute__((ext_vector_type(4)));
typedef _Float16 half2v __attribute__((ext_vector_type(2)));
typedef float float4v __attribute__((ext_vector_type(4)));

__device__ __forceinline__ float lrelu(float v) { return v > 0.f ? v : NEG_SLOPE * v; }

// ---------------- W transpose+convert: wt[l][col][k] = W_l[k][col] fp16 ----
__global__ void convw_kernel(const float* __restrict__ W0, const float* __restrict__ W1,
                             _Float16* __restrict__ wt)
{
    int i = blockIdx.x * 256 + threadIdx.x;
    if (i >= 2 * IN_DIM * HCH) return;
    int l = i >> 15, rem = i & 32767;
    int c = rem >> 8, k = rem & 255;
    const float* W = l ? W1 : W0;
    wt[i] = (_Float16)W[(size_t)k * HCH + c];
}

// ---------------- fused GEMM (fp16 MFMA) + attention-score epilogue --------
// h16[n][128] = fp16(x[n][256] @ W); a_s/a_d[n][2] = h·att_src / h·att_dst
// block 256 thr = 4 waves; tile 128x128; wave tile 64x64 (4x4 of 16x16x32)
__global__ __launch_bounds__(256, 4) void gemm_mfma(
    const float* __restrict__ x, const _Float16* __restrict__ wt,
    const float* __restrict__ att_src, const float* __restrict__ att_dst,
    _Float16* __restrict__ h16, float* __restrict__ a_s, float* __restrict__ a_d, int n)
{
    __shared__ _Float16 smem[2][128][72];   // [0]=A rows x k, [1]=B cols x k (pad 8)
    __shared__ float attv[2][128];
    const int tid = threadIdx.x;
    const int lane = tid & 63, wave = tid >> 6;
    const int wm = wave & 1, wn = wave >> 1;
    const int q = lane >> 4, r16 = lane & 15;
    const int row0 = blockIdx.x * 128;

    if (tid < 128) { attv[0][tid] = att_src[tid]; attv[1][tid] = att_dst[tid]; }

    float4v acc[4][4];
#pragma unroll
    for (int i = 0; i < 4; ++i)
#pragma unroll
        for (int j = 0; j < 4; ++j) acc[i][j] = (float4v){0.f, 0.f, 0.f, 0.f};

    const int ar = tid >> 1, ah = tid & 1;
    const bool rok = (row0 + ar) < n;
    for (int kt = 0; kt < IN_DIM; kt += 64) {
        // stage A: x fp32 -> fp16, rows 0..127 x k 0..63
        const float* xp = x + (size_t)(row0 + ar) * IN_DIM + kt + ah * 32;
#pragma unroll
        for (int i = 0; i < 8; ++i) {
            float4 v = rok ? *(const float4*)(xp + i * 4) : make_float4(0.f, 0.f, 0.f, 0.f);
            half4v hv = { (_Float16)v.x, (_Float16)v.y, (_Float16)v.z, (_Float16)v.w };
            *(half4v*)&smem[0][ar][ah * 32 + i * 4] = hv;
        }
        // stage B: wt cols 0..127 x k 0..63 (already fp16, k-contiguous)
        const _Float16* wp = wt + (size_t)ar * IN_DIM + kt + ah * 32;
#pragma unroll
        for (int i = 0; i < 4; ++i)
            *(half8v*)&smem[1][ar][ah * 32 + i * 8] = *(const half8v*)(wp + i * 8);
        __syncthreads();
#pragma unroll
        for (int s = 0; s < 2; ++s) {
            half8v af[4], bf[4];
#pragma unroll
            for (int t = 0; t < 4; ++t) {
                af[t] = *(half8v*)&smem[0][wm * 64 + t * 16 + r16][s * 32 + q * 8];
                bf[t] = *(half8v*)&smem[1][wn * 64 + t * 16 + r16][s * 32 + q * 8];
            }
#pragma unroll
            for (int mt = 0; mt < 4; ++mt)
#pragma unroll
                for (int nt = 0; nt < 4; ++nt)
                    acc[mt][nt] = __builtin_amdgcn_mfma_f32_16x16x32_f16(
                        af[mt], bf[nt], acc[mt][nt], 0, 0, 0);
        }
        __syncthreads();
    }
    // epilogue: repack C to fp16 via LDS (C layout: row=q*4+reg, col=r16)
    _Float16 (*eb)[136] = (_Float16(*)[136]) & smem[0][0][0];  // 128x136 fits in smem
#pragma unroll
    for (int mt = 0; mt < 4; ++mt) {
        const int er = wm * 64 + mt * 16 + q * 4;
#pragma unroll
        for (int reg = 0; reg < 4; ++reg)
#pragma unroll
            for (int nt = 0; nt < 4; ++nt)
                eb[er + reg][wn * 64 + nt * 16 + r16] = (_Float16)acc[mt][nt][reg];
    }
    __syncthreads();
    // coalesced h16 store + fused attention dot (half hh == head hh)
    const int r = tid >> 1, hh = tid & 1;
    const int grow = row0 + r;
    if (grow < n) {
        float ds = 0.f, dd = 0.f;
#pragma unroll
        for (int i = 0; i < 8; ++i) {
            half8v v = *(half8v*)&eb[r][hh * 64 + i * 8];
            *(half8v*)(h16 + (size_t)grow * HCH + hh * 64 + i * 8) = v;
#pragma unroll
            for (int j = 0; j < 8; ++j) {
                float f = (float)v[j];
                ds = fmaf(f, attv[0][hh * 64 + i * 8 + j], ds);
                dd = fmaf(f, attv[1][hh * 64 + i * 8 + j], dd);
            }
        }
        a_s[2 * grow + hh] = ds;
        a_d[2 * grow + hh] = dd;
    }
}

// ---------------- CSR build ----------------
__global__ void hist_kernel(const int* __restrict__ dst, int* __restrict__ counts, int e)
{
    int i = blockIdx.x * blockDim.x + threadIdx.x;
    if (i < e) atomicAdd(&counts[dst[i]], 1);
}

__global__ __launch_bounds__(256) void scan1_kernel(const int* __restrict__ counts,
                                                    int* __restrict__ indptr,
                                                    int* __restrict__ bsums, int n)
{
    __shared__ int sd[256];
    int tid = threadIdx.x;
    int i0 = blockIdx.x * 1024 + tid * 4;
    int c[4];
#pragma unroll
    for (int j = 0; j < 4; ++j) c[j] = (i0 + j < n) ? counts[i0 + j] : 0;
    int ts = c[0] + c[1] + c[2] + c[3];
    sd[tid] = ts;
    __syncthreads();
    int v = ts;
    for (int off = 1; off < 256; off <<= 1) {
        int t = (tid >= off) ? sd[tid - off] : 0;
        __syncthreads();
        v += t;
        sd[tid] = v;
        __syncthreads();
    }
    int e0 = v - ts;
#pragma unroll
    for (int j = 0; j < 4; ++j) {
        if (i0 + j < n) indptr[i0 + j] = e0;
        e0 += c[j];
    }
    if (tid == 255) bsums[blockIdx.x] = sd[255];
}

__global__ __launch_bounds__(128) void scan2_kernel(int* bsums, int nb)
{
    __shared__ int sd[128];
    int tid = threadIdx.x;
    int v0 = (tid < nb) ? bsums[tid] : 0;
    sd[tid] = v0;
    __syncthreads();
    int v = v0;
    for (int off = 1; off < 128; off <<= 1) {
        int t = (tid >= off) ? sd[tid - off] : 0;
        __syncthreads();
        v += t;
        sd[tid] = v;
        __syncthreads();
    }
    if (tid < nb) bsums[tid] = v - v0;
}

__global__ void scan3_kernel(int* __restrict__ indptr, int* __restrict__ cursor,
                             const int* __restrict__ bsums, int n, int etot)
{
    int i = blockIdx.x * blockDim.x + threadIdx.x;
    if (i < n) {
        int v = indptr[i] + bsums[i >> 10];
        indptr[i] = v;
        cursor[i] = v;
    } else if (i == n) {
        indptr[n] = etot;
    }
}

__global__ void scatter_kernel(const int* __restrict__ src, const int* __restrict__ dst,
                               int* __restrict__ cursor, int* __restrict__ ssrc, int e)
{
    int i = blockIdx.x * blockDim.x + threadIdx.x;
    if (i < e) {
        int pos = atomicAdd(&cursor[dst[i]], 1);
        ssrc[pos] = src[i];
    }
}

// ---------------- per-node softmax aggregation (fp16 gather) ----------------
__global__ __launch_bounds__(256) void agg_kernel(
    const _Float16* __restrict__ h16, const float2* __restrict__ a_s,
    const float2* __restrict__ a_d, const int* __restrict__ indptr,
    const int* __restrict__ ssrc, const float* __restrict__ bias,
    _Float16* __restrict__ xc16, int n)
{
    __shared__ float4 sh[4][64];
    const int wid = threadIdx.x >> 6, lane = threadIdx.x & 63;
    const int node = blockIdx.x * 4 + wid;
    const bool valid = node < n;
    const int nn = valid ? node : 0;
    const int start = indptr[nn], end = indptr[nn + 1];
    const float2 ad = a_d[nn];
    const float2 asn = a_s[nn];

    float acc0 = 0.f, acc1 = 0.f;
    float s0 = 0.f, s1 = 0.f;

    for (int base = start; base < end; base += 64) {
        const int j = base + lane;
        const int cnt = min(64, end - base);
        float p0 = 0.f, p1 = 0.f;
        int s = 0;
        if (j < end) {
            s = ssrc[j];
            float2 a = a_s[s];
            p0 = __expf(lrelu(a.x + ad.x));
            p1 = __expf(lrelu(a.y + ad.y));
        }
        s0 += p0;
        s1 += p1;
        sh[wid][lane] = make_float4(__int_as_float(s), p0, p1, 0.f);
        __builtin_amdgcn_wave_barrier();
        for (int t = 0; t < cnt; ++t) {
            const float4 e = sh[wid][t];
            const half2v hv =
                *(const half2v*)(h16 + (size_t)__float_as_int(e.x) * HCH + 2 * lane);
            const float pl = (lane < 32) ? e.y : e.z;
            acc0 = fmaf(pl, (float)hv[0], acc0);
            acc1 = fmaf(pl, (float)hv[1], acc1);
        }
        __builtin_amdgcn_wave_barrier();
    }
    // self loop
    {
        const float ps0 = __expf(lrelu(asn.x + ad.x));
        const float ps1 = __expf(lrelu(asn.y + ad.y));
        const half2v hv = *(const half2v*)(h16 + (size_t)nn * HCH + 2 * lane);
        const float pl = (lane < 32) ? ps0 : ps1;
        acc0 = fmaf(pl, (float)hv[0], acc0);
        acc1 = fmaf(pl, (float)hv[1], acc1);
        if (lane == 0) { s0 += ps0; s1 += ps1; }
    }
#pragma unroll
    for (int m = 32; m >= 1; m >>= 1) {
        s0 += __shfl_xor(s0, m, 64);
        s1 += __shfl_xor(s1, m, 64);
    }
    const float dl = (lane < 32) ? s0 : s1;
    if (valid) {
        const float o0 = fmaxf(acc0 / dl + bias[2 * lane], 0.f);
        const float o1 = fmaxf(acc1 / dl + bias[2 * lane + 1], 0.f);
        half2v o = { (_Float16)o0, (_Float16)o1 };
        *(half2v*)(xc16 + (size_t)node * HCH + 2 * lane) = o;
    }
}

// ---------------- FC half: out (+)= xc16[N,128] @ fcW_half[128,64] (+ fcb) --
__global__ __launch_bounds__(256) void fc_kernel(const _Float16* __restrict__ xc16,
                                                 const float* __restrict__ fw,
                                                 const float* __restrict__ fcb,
                                                 float* __restrict__ out, int n, int beta)
{
    __shared__ float xcs[32][132];
    __shared__ float fws[32][64];
    const int tid = threadIdx.x;
    const int tx = tid & 15;
    const int ty = tid >> 4;
    const int row0 = blockIdx.x * 128;

    float acc[8][4];
#pragma unroll
    for (int i = 0; i < 8; ++i)
#pragma unroll
        for (int j = 0; j < 4; ++j) acc[i][j] = 0.f;

    for (int kt = 0; kt < HCH; kt += 32) {
        // stage xc16 tile transposed: 128 rows x 32 k (512 half8 loads, 2/thread)
#pragma unroll
        for (int i = 0; i < 2; ++i) {
            const int idx = i * 256 + tid;
            const int row = idx >> 2;
            const int cg = (idx & 3) * 8;
            half8v v = { 0, 0, 0, 0, 0, 0, 0, 0 };
            if (row0 + row < n)
                v = *(const half8v*)(xc16 + (size_t)(row0 + row) * HCH + kt + cg);
#pragma unroll
            for (int j = 0; j < 8; ++j) xcs[cg + j][row] = (float)v[j];
        }
        // stage fw tile: 32 x 64 = 512 float4s, 2/thread
#pragma unroll
        for (int r = 0; r < 2; ++r) {
            const int idx = r * 256 + tid;
            const int k = idx >> 4;
            const int c = (idx & 15) * 4;
            *(float4*)&fws[k][c] = *(const float4*)(fw + (size_t)(kt + k) * OUT_DIM + c);
        }
        __syncthreads();
#pragma unroll
        for (int k = 0; k < 32; ++k) {
            const float4 a0 = *(float4*)&xcs[k][ty * 8];
            const float4 a1 = *(float4*)&xcs[k][ty * 8 + 4];
            const float4 b = *(float4*)&fws[k][tx * 4];
            const float av[8] = { a0.x, a0.y, a0.z, a0.w, a1.x, a1.y, a1.z, a1.w };
            const float bv[4] = { b.x, b.y, b.z, b.w };
#pragma unroll
            for (int i = 0; i < 8; ++i)
#pragma unroll
                for (int j = 0; j < 4; ++j)
                    acc[i][j] = fmaf(av[i], bv[j], acc[i][j]);
        }
        __syncthreads();
    }
    const float4 bb = *(const float4*)(fcb + tx * 4);
#pragma unroll
    for (int i = 0; i < 8; ++i) {
        const int row = row0 + ty * 8 + i;
        if (row < n) {
            float4 v = make_float4(acc[i][0], acc[i][1], acc[i][2], acc[i][3]);
            if (beta) {
                const float4 o = *(const float4*)(out + (size_t)row * OUT_DIM + tx * 4);
                v.x += o.x; v.y += o.y; v.z += o.z; v.w += o.w;
            } else {
                v.x += bb.x; v.y += bb.y; v.z += bb.z; v.w += bb.w;
            }
            *(float4*)(out + (size_t)row * OUT_DIM + tx * 4) = v;
        }
    }
}

// ---------------- launch ----------------
extern "C" void kernel_launch(void* const* d_in, const int* in_sizes, int n_in,
                              void* d_out, int out_size, void* d_ws, size_t ws_size,
                              hipStream_t stream)
{
    const float* x = (const float*)d_in[0];
    const int* ei[2] = { (const int*)d_in[1], (const int*)d_in[2] };
    const float* W[2] = { (const float*)d_in[3], (const float*)d_in[7] };
    const float* attS[2] = { (const float*)d_in[4], (const float*)d_in[8] };
    const float* attD[2] = { (const float*)d_in[5], (const float*)d_in[9] };
    const float* bias[2] = { (const float*)d_in[6], (const float*)d_in[10] };
    const float* fcW = (const float*)d_in[11];
    const float* fcb = (const float*)d_in[12];
    float* out = (float*)d_out;

    char* p = (char*)d_ws;
    size_t need = 0;
    auto carve = [&](size_t bytes) {
        char* r = p;
        size_t b = (bytes + 255) & ~(size_t)255;
        p += b;
        need += b;
        return r;
    };
    _Float16* h16 = (_Float16*)carve((size_t)NN * HCH * 2);
    _Float16* xc16 = (_Float16*)carve((size_t)NN * HCH * 2);
    _Float16* wt = (_Float16*)carve((size_t)2 * IN_DIM * HCH * 2);
    float* a_s = (float*)carve((size_t)NN * 8);
    float* a_d = (float*)carve((size_t)NN * 8);
    int* counts = (int*)carve((size_t)NN * 4);
    int* indptr = (int*)carve((size_t)(NN + 1) * 4);
    int* cursor = (int*)carve((size_t)NN * 4);
    int* bsums = (int*)carve(1024);
    int* ssrc = (int*)carve((size_t)EE * 4);
    if (need > ws_size) return;  // loud correctness failure instead of OOB crash

    const int gemm_blocks = (NN + 127) / 128;      // 782
    const int node_blocks = (NN + 3) / 4;          // 25000
    const int edge_blocks = (EE + 255) / 256;      // 6250
    const int scan_blocks = (NN + 1023) / 1024;    // 98
    const int scan3_blocks = (NN + 1 + 255) / 256; // 391

    convw_kernel<<<(2 * IN_DIM * HCH + 255) / 256, 256, 0, stream>>>(W[0], W[1], wt);

    for (int layer = 0; layer < 2; ++layer) {
        gemm_mfma<<<gemm_blocks, 256, 0, stream>>>(x, wt + (size_t)layer * IN_DIM * HCH,
                                                   attS[layer], attD[layer],
                                                   h16, a_s, a_d, NN);
        hipMemsetAsync(counts, 0, (size_t)NN * 4, stream);
        hist_kernel<<<edge_blocks, 256, 0, stream>>>(ei[layer] + EE, counts, EE);
        scan1_kernel<<<scan_blocks, 256, 0, stream>>>(counts, indptr, bsums, NN);
        scan2_kernel<<<1, 128, 0, stream>>>(bsums, scan_blocks);
        scan3_kernel<<<scan3_blocks, 256, 0, stream>>>(indptr, cursor, bsums, NN, EE);
        scatter_kernel<<<edge_blocks, 256, 0, stream>>>(ei[layer], ei[layer] + EE, cursor, ssrc, EE);
        agg_kernel<<<node_blocks, 256, 0, stream>>>(h16, (const float2*)a_s, (const float2*)a_d,
                                                    indptr, ssrc, bias[layer], xc16, NN);
        fc_kernel<<<gemm_blocks, 256, 0, stream>>>(xc16, fcW + (size_t)layer * HCH * OUT_DIM,
                                                   fcb, out, NN, layer);
    }
}

// Round 4
// 802.921 us; speedup vs baseline: 1.6129x; 1.0928x over previous
//
#include <hip/hip_runtime.h>
#include <hip/hip_fp16.h>
#include <math.h>

#define NN 100000
#define IN_DIM 256
#define HCH 128      // HEADS*HID
#define OUT_DIM 64
#define EE 1600000
#define NEG_SLOPE 0.2f

#define NB 1024      // dst buckets
#define NPB 98       // nodes per bucket (1024*98 >= 100000)
#define CAP 2048     // bucket capacity (mean 1562, std ~40 -> 12 sigma margin)

typedef _Float16 half8v __attribute__((ext_vector_type(8)));
typedef _Float16 half4v __attribute__((ext_vector_type(4)));
typedef _Float16 half2v __attribute__((ext_vector_type(2)));
typedef float float4v __attribute__((ext_vector_type(4)));

__device__ __forceinline__ float lrelu(float v) { return v > 0.f ? v : NEG_SLOPE * v; }

// ---------------- W transpose+convert: wt[l][col][k] = W_l[k][col] fp16 ----
__global__ void convw_kernel(const float* __restrict__ W0, const float* __restrict__ W1,
                             _Float16* __restrict__ wt)
{
    int i = blockIdx.x * 256 + threadIdx.x;
    if (i >= 2 * IN_DIM * HCH) return;
    int l = i >> 15, rem = i & 32767;
    int c = rem >> 8, k = rem & 255;
    const float* W = l ? W1 : W0;
    wt[i] = (_Float16)W[(size_t)k * HCH + c];
}

// ---------------- fused GEMM (fp16 MFMA) + attention-score epilogue --------
__global__ __launch_bounds__(256, 4) void gemm_mfma(
    const float* __restrict__ x, const _Float16* __restrict__ wt,
    const float* __restrict__ att_src, const float* __restrict__ att_dst,
    _Float16* __restrict__ h16, float* __restrict__ a_s, float* __restrict__ a_d, int n)
{
    __shared__ _Float16 smem[2][128][72];   // [0]=A rows x k, [1]=B cols x k (pad 8)
    __shared__ float attv[2][128];
    const int tid = threadIdx.x;
    const int lane = tid & 63, wave = tid >> 6;
    const int wm = wave & 1, wn = wave >> 1;
    const int q = lane >> 4, r16 = lane & 15;
    const int row0 = blockIdx.x * 128;

    if (tid < 128) { attv[0][tid] = att_src[tid]; attv[1][tid] = att_dst[tid]; }

    float4v acc[4][4];
#pragma unroll
    for (int i = 0; i < 4; ++i)
#pragma unroll
        for (int j = 0; j < 4; ++j) acc[i][j] = (float4v){0.f, 0.f, 0.f, 0.f};

    const int ar = tid >> 1, ah = tid & 1;
    const bool rok = (row0 + ar) < n;
    for (int kt = 0; kt < IN_DIM; kt += 64) {
        const float* xp = x + (size_t)(row0 + ar) * IN_DIM + kt + ah * 32;
#pragma unroll
        for (int i = 0; i < 8; ++i) {
            float4 v = rok ? *(const float4*)(xp + i * 4) : make_float4(0.f, 0.f, 0.f, 0.f);
            half4v hv = { (_Float16)v.x, (_Float16)v.y, (_Float16)v.z, (_Float16)v.w };
            *(half4v*)&smem[0][ar][ah * 32 + i * 4] = hv;
        }
        const _Float16* wp = wt + (size_t)ar * IN_DIM + kt + ah * 32;
#pragma unroll
        for (int i = 0; i < 4; ++i)
            *(half8v*)&smem[1][ar][ah * 32 + i * 8] = *(const half8v*)(wp + i * 8);
        __syncthreads();
#pragma unroll
        for (int s = 0; s < 2; ++s) {
            half8v af[4], bf[4];
#pragma unroll
            for (int t = 0; t < 4; ++t) {
                af[t] = *(half8v*)&smem[0][wm * 64 + t * 16 + r16][s * 32 + q * 8];
                bf[t] = *(half8v*)&smem[1][wn * 64 + t * 16 + r16][s * 32 + q * 8];
            }
#pragma unroll
            for (int mt = 0; mt < 4; ++mt)
#pragma unroll
                for (int nt = 0; nt < 4; ++nt)
                    acc[mt][nt] = __builtin_amdgcn_mfma_f32_16x16x32_f16(
                        af[mt], bf[nt], acc[mt][nt], 0, 0, 0);
        }
        __syncthreads();
    }
    // epilogue: repack C to fp16 via LDS (C layout: row=q*4+reg, col=r16)
    _Float16 (*eb)[136] = (_Float16(*)[136]) & smem[0][0][0];
#pragma unroll
    for (int mt = 0; mt < 4; ++mt) {
        const int er = wm * 64 + mt * 16 + q * 4;
#pragma unroll
        for (int reg = 0; reg < 4; ++reg)
#pragma unroll
            for (int nt = 0; nt < 4; ++nt)
                eb[er + reg][wn * 64 + nt * 16 + r16] = (_Float16)acc[mt][nt][reg];
    }
    __syncthreads();
    const int r = tid >> 1, hh = tid & 1;
    const int grow = row0 + r;
    if (grow < n) {
        float ds = 0.f, dd = 0.f;
#pragma unroll
        for (int i = 0; i < 8; ++i) {
            half8v v = *(half8v*)&eb[r][hh * 64 + i * 8];
            *(half8v*)(h16 + (size_t)grow * HCH + hh * 64 + i * 8) = v;
#pragma unroll
            for (int j = 0; j < 8; ++j) {
                float f = (float)v[j];
                ds = fmaf(f, attv[0][hh * 64 + i * 8 + j], ds);
                dd = fmaf(f, attv[1][hh * 64 + i * 8 + j], dd);
            }
        }
        a_s[2 * grow + hh] = ds;
        a_d[2 * grow + hh] = dd;
    }
}

// ---------------- bucket edges by dst region ----------------
// LDS histogram -> one reserve atomic per (block,bucket) -> packed append
__global__ __launch_bounds__(256) void bucket_kernel(const int* __restrict__ src,
                                                     const int* __restrict__ dst,
                                                     int* __restrict__ gcursor,
                                                     int* __restrict__ bstore, int e)
{
    __shared__ int hist[NB];
    __shared__ int base[NB];
    const int tid = threadIdx.x;
    const int per = (e + gridDim.x - 1) / gridDim.x;
    const int e0 = blockIdx.x * per;
    const int e1 = min(e, e0 + per);
    for (int i = tid; i < NB; i += 256) hist[i] = 0;
    __syncthreads();
    for (int i = e0 + tid; i < e1; i += 256)
        atomicAdd(&hist[dst[i] / NPB], 1);
    __syncthreads();
    for (int b = tid; b < NB; b += 256) {
        int c = hist[b];
        base[b] = c ? atomicAdd(&gcursor[b], c) : 0;
        hist[b] = 0;
    }
    __syncthreads();
    for (int i = e0 + tid; i < e1; i += 256) {
        int d = dst[i];
        int s = src[i];
        int b = d / NPB;
        int pos = base[b] + atomicAdd(&hist[b], 1);
        if (pos < CAP) bstore[b * CAP + pos] = (s << 7) | (d - b * NPB);
    }
}

// ---------------- per-bucket LDS counting sort + softmax aggregation --------
__global__ __launch_bounds__(256) void aggsort_kernel(
    const _Float16* __restrict__ h16, const float2* __restrict__ a_s,
    const float2* __restrict__ a_d, const int* __restrict__ gcursor,
    const int* __restrict__ bstore, const float* __restrict__ bias,
    _Float16* __restrict__ xc16, int n)
{
    __shared__ int raw[CAP];
    __shared__ int sorted[CAP];
    __shared__ int scanbuf[128];
    __shared__ int startp[NPB + 1];
    __shared__ int curs[NPB];
    __shared__ float4 sh[4][64];
    const int tid = threadIdx.x;
    const int b = blockIdx.x;
    const int node0 = b * NPB;
    const int nnode = min(NPB, n - node0);
    if (nnode <= 0) return;
    const int cnt = min(gcursor[b], CAP);

    for (int i = tid; i < cnt; i += 256) raw[i] = bstore[b * CAP + i];
    if (tid < NPB) curs[tid] = 0;
    __syncthreads();
    for (int i = tid; i < cnt; i += 256) atomicAdd(&curs[raw[i] & 127], 1);
    __syncthreads();
    // inclusive scan over 128 (NPB padded) -> exclusive startp
    if (tid < 128) scanbuf[tid] = (tid < NPB) ? curs[tid] : 0;
    __syncthreads();
    for (int off = 1; off < 128; off <<= 1) {
        int v = 0;
        if (tid < 128) { v = scanbuf[tid]; if (tid >= off) v += scanbuf[tid - off]; }
        __syncthreads();
        if (tid < 128) scanbuf[tid] = v;
        __syncthreads();
    }
    if (tid < NPB) {
        int ex = tid ? scanbuf[tid - 1] : 0;
        startp[tid] = ex;
        curs[tid] = ex;
    }
    if (tid == 0) startp[NPB] = scanbuf[NPB - 1];
    __syncthreads();
    for (int i = tid; i < cnt; i += 256) {
        int item = raw[i];
        int pos = atomicAdd(&curs[item & 127], 1);
        sorted[pos] = item >> 7;
    }
    __syncthreads();

    const int wid = tid >> 6, lane = tid & 63;
    for (int ld = wid; ld < nnode; ld += 4) {
        const int node = node0 + ld;
        const int start = startp[ld], end = startp[ld + 1];
        const float2 ad = a_d[node];
        const float2 asn = a_s[node];
        float acc0 = 0.f, acc1 = 0.f, s0 = 0.f, s1 = 0.f;

        for (int base_ = start; base_ < end; base_ += 64) {
            const int j = base_ + lane;
            const int c = min(64, end - base_);
            float p0 = 0.f, p1 = 0.f;
            int s = 0;
            if (j < end) {
                s = sorted[j];
                float2 a = a_s[s];
                p0 = __expf(lrelu(a.x + ad.x));
                p1 = __expf(lrelu(a.y + ad.y));
            }
            s0 += p0;
            s1 += p1;
            sh[wid][lane] = make_float4(__int_as_float(s), p0, p1, 0.f);
            __builtin_amdgcn_wave_barrier();
            for (int t = 0; t < c; ++t) {
                const float4 e = sh[wid][t];
                const half2v hv =
                    *(const half2v*)(h16 + (size_t)__float_as_int(e.x) * HCH + 2 * lane);
                const float pl = (lane < 32) ? e.y : e.z;
                acc0 = fmaf(pl, (float)hv[0], acc0);
                acc1 = fmaf(pl, (float)hv[1], acc1);
            }
            __builtin_amdgcn_wave_barrier();
        }
        // self loop
        {
            const float ps0 = __expf(lrelu(asn.x + ad.x));
            const float ps1 = __expf(lrelu(asn.y + ad.y));
            const half2v hv = *(const half2v*)(h16 + (size_t)node * HCH + 2 * lane);
            const float pl = (lane < 32) ? ps0 : ps1;
            acc0 = fmaf(pl, (float)hv[0], acc0);
            acc1 = fmaf(pl, (float)hv[1], acc1);
            if (lane == 0) { s0 += ps0; s1 += ps1; }
        }
        float r0 = s0, r1 = s1;
#pragma unroll
        for (int m = 32; m >= 1; m >>= 1) {
            r0 += __shfl_xor(r0, m, 64);
            r1 += __shfl_xor(r1, m, 64);
        }
        const float dl = (lane < 32) ? r0 : r1;
        const float o0 = fmaxf(acc0 / dl + bias[2 * lane], 0.f);
        const float o1 = fmaxf(acc1 / dl + bias[2 * lane + 1], 0.f);
        half2v o = { (_Float16)o0, (_Float16)o1 };
        *(half2v*)(xc16 + (size_t)node * HCH + 2 * lane) = o;
    }
}

// ---------------- fused FC: out = [xc0|xc1] @ fcW + fcb ----------------
__global__ __launch_bounds__(256) void fc2_kernel(const _Float16* __restrict__ xc0,
                                                  const _Float16* __restrict__ xc1,
                                                  const float* __restrict__ fcW,
                                                  const float* __restrict__ fcb,
                                                  float* __restrict__ out, int n)
{
    __shared__ float xcs[32][132];
    __shared__ float fws[32][64];
    const int tid = threadIdx.x;
    const int tx = tid & 15;
    const int ty = tid >> 4;
    const int row0 = blockIdx.x * 128;

    float acc[8][4];
#pragma unroll
    for (int i = 0; i < 8; ++i)
#pragma unroll
        for (int j = 0; j < 4; ++j) acc[i][j] = 0.f;

    for (int kt = 0; kt < 2 * HCH; kt += 32) {
        const _Float16* xs_ = (kt < HCH) ? xc0 : xc1;
        const int kk = kt & (HCH - 1);
#pragma unroll
        for (int i = 0; i < 2; ++i) {
            const int idx = i * 256 + tid;
            const int row = idx >> 2;
            const int cg = (idx & 3) * 8;
            half8v v = { 0, 0, 0, 0, 0, 0, 0, 0 };
            if (row0 + row < n)
                v = *(const half8v*)(xs_ + (size_t)(row0 + row) * HCH + kk + cg);
#pragma unroll
            for (int j = 0; j < 8; ++j) xcs[cg + j][row] = (float)v[j];
        }
#pragma unroll
        for (int r = 0; r < 2; ++r) {
            const int idx = r * 256 + tid;
            const int k = idx >> 4;
            const int c = (idx & 15) * 4;
            *(float4*)&fws[k][c] = *(const float4*)(fcW + (size_t)(kt + k) * OUT_DIM + c);
        }
        __syncthreads();
#pragma unroll
        for (int k = 0; k < 32; ++k) {
            const float4 a0 = *(float4*)&xcs[k][ty * 8];
            const float4 a1 = *(float4*)&xcs[k][ty * 8 + 4];
            const float4 bq = *(float4*)&fws[k][tx * 4];
            const float av[8] = { a0.x, a0.y, a0.z, a0.w, a1.x, a1.y, a1.z, a1.w };
            const float bv[4] = { bq.x, bq.y, bq.z, bq.w };
#pragma unroll
            for (int i = 0; i < 8; ++i)
#pragma unroll
                for (int j = 0; j < 4; ++j)
                    acc[i][j] = fmaf(av[i], bv[j], acc[i][j]);
        }
        __syncthreads();
    }
    const float4 bb = *(const float4*)(fcb + tx * 4);
#pragma unroll
    for (int i = 0; i < 8; ++i) {
        const int row = row0 + ty * 8 + i;
        if (row < n) {
            float4 v = make_float4(acc[i][0] + bb.x, acc[i][1] + bb.y,
                                   acc[i][2] + bb.z, acc[i][3] + bb.w);
            *(float4*)(out + (size_t)row * OUT_DIM + tx * 4) = v;
        }
    }
}

// ---------------- launch ----------------
extern "C" void kernel_launch(void* const* d_in, const int* in_sizes, int n_in,
                              void* d_out, int out_size, void* d_ws, size_t ws_size,
                              hipStream_t stream)
{
    const float* x = (const float*)d_in[0];
    const int* ei[2] = { (const int*)d_in[1], (const int*)d_in[2] };
    const float* W[2] = { (const float*)d_in[3], (const float*)d_in[7] };
    const float* attS[2] = { (const float*)d_in[4], (const float*)d_in[8] };
    const float* attD[2] = { (const float*)d_in[5], (const float*)d_in[9] };
    const float* bias[2] = { (const float*)d_in[6], (const float*)d_in[10] };
    const float* fcW = (const float*)d_in[11];
    const float* fcb = (const float*)d_in[12];
    float* out = (float*)d_out;

    char* p = (char*)d_ws;
    size_t need = 0;
    auto carve = [&](size_t bytes) {
        char* r = p;
        size_t b = (bytes + 255) & ~(size_t)255;
        p += b;
        need += b;
        return r;
    };
    _Float16* h16 = (_Float16*)carve((size_t)NN * HCH * 2);
    _Float16* xc0 = (_Float16*)carve((size_t)NN * HCH * 2);
    _Float16* xc1 = (_Float16*)carve((size_t)NN * HCH * 2);
    _Float16* wt = (_Float16*)carve((size_t)2 * IN_DIM * HCH * 2);
    float* a_s = (float*)carve((size_t)NN * 8);
    float* a_d = (float*)carve((size_t)NN * 8);
    int* gcursor = (int*)carve((size_t)NB * 4);
    int* bstore = (int*)carve((size_t)NB * CAP * 4);
    if (need > ws_size) return;  // loud correctness failure instead of OOB crash

    _Float16* xc[2] = { xc0, xc1 };
    const int gemm_blocks = (NN + 127) / 128;   // 782

    convw_kernel<<<(2 * IN_DIM * HCH + 255) / 256, 256, 0, stream>>>(W[0], W[1], wt);

    for (int layer = 0; layer < 2; ++layer) {
        gemm_mfma<<<gemm_blocks, 256, 0, stream>>>(x, wt + (size_t)layer * IN_DIM * HCH,
                                                   attS[layer], attD[layer],
                                                   h16, a_s, a_d, NN);
        hipMemsetAsync(gcursor, 0, (size_t)NB * 4, stream);
        bucket_kernel<<<128, 256, 0, stream>>>(ei[layer], ei[layer] + EE, gcursor, bstore, EE);
        aggsort_kernel<<<NB, 256, 0, stream>>>(h16, (const float2*)a_s, (const float2*)a_d,
                                               gcursor, bstore, bias[layer], xc[layer], NN);
    }
    fc2_kernel<<<gemm_blocks, 256, 0, stream>>>(xc0, xc1, fcW, fcb, out, NN);
}

// Round 6
// 604.590 us; speedup vs baseline: 2.1420x; 1.3280x over previous
//
#include <hip/hip_runtime.h>
#include <hip/hip_fp16.h>
#include <math.h>

#define NN 100000
#define IN_DIM 256
#define HCH 128      // HEADS*HID
#define OUT_DIM 64
#define EE 1600000
#define NEG_SLOPE 0.2f

#define NB 1024      // dst buckets
#define NPB 98       // nodes per bucket (1024*98 >= 100000)
#define CAP 2048     // bucket capacity (mean 1562, std ~40 -> 12 sigma margin)

typedef _Float16 half8v __attribute__((ext_vector_type(8)));
typedef _Float16 half4v __attribute__((ext_vector_type(4)));
typedef _Float16 half2v __attribute__((ext_vector_type(2)));
typedef float float4v __attribute__((ext_vector_type(4)));

__device__ __forceinline__ float lrelu(float v) { return v > 0.f ? v : NEG_SLOPE * v; }

// ---------------- W transpose+convert: wt[l][col][k] = W_l[k][col] fp16 ----
__global__ void convw_kernel(const float* __restrict__ W0, const float* __restrict__ W1,
                             _Float16* __restrict__ wt)
{
    int i = blockIdx.x * 256 + threadIdx.x;
    if (i >= 2 * IN_DIM * HCH) return;
    int l = i >> 15, rem = i & 32767;
    int c = rem >> 8, k = rem & 255;
    const float* W = l ? W1 : W0;
    wt[i] = (_Float16)W[(size_t)k * HCH + c];
}

// ---------------- fused GEMM (fp16 MFMA) + attention-score epilogue --------
__global__ __launch_bounds__(256, 4) void gemm_mfma(
    const float* __restrict__ x, const _Float16* __restrict__ wt,
    const float* __restrict__ att_src, const float* __restrict__ att_dst,
    _Float16* __restrict__ h16, float* __restrict__ a_s, float* __restrict__ a_d, int n)
{
    __shared__ _Float16 smem[2][128][72];   // [0]=A rows x k, [1]=B cols x k (pad 8)
    __shared__ float attv[2][128];
    const int tid = threadIdx.x;
    const int lane = tid & 63, wave = tid >> 6;
    const int wm = wave & 1, wn = wave >> 1;
    const int q = lane >> 4, r16 = lane & 15;
    const int row0 = blockIdx.x * 128;

    if (tid < 128) { attv[0][tid] = att_src[tid]; attv[1][tid] = att_dst[tid]; }

    float4v acc[4][4];
#pragma unroll
    for (int i = 0; i < 4; ++i)
#pragma unroll
        for (int j = 0; j < 4; ++j) acc[i][j] = (float4v){0.f, 0.f, 0.f, 0.f};

    const int ar = tid >> 1, ah = tid & 1;
    const bool rok = (row0 + ar) < n;
    for (int kt = 0; kt < IN_DIM; kt += 64) {
        const float* xp = x + (size_t)(row0 + ar) * IN_DIM + kt + ah * 32;
#pragma unroll
        for (int i = 0; i < 8; ++i) {
            float4 v = rok ? *(const float4*)(xp + i * 4) : make_float4(0.f, 0.f, 0.f, 0.f);
            half4v hv = { (_Float16)v.x, (_Float16)v.y, (_Float16)v.z, (_Float16)v.w };
            *(half4v*)&smem[0][ar][ah * 32 + i * 4] = hv;
        }
        const _Float16* wp = wt + (size_t)ar * IN_DIM + kt + ah * 32;
#pragma unroll
        for (int i = 0; i < 4; ++i)
            *(half8v*)&smem[1][ar][ah * 32 + i * 8] = *(const half8v*)(wp + i * 8);
        __syncthreads();
#pragma unroll
        for (int s = 0; s < 2; ++s) {
            half8v af[4], bf[4];
#pragma unroll
            for (int t = 0; t < 4; ++t) {
                af[t] = *(half8v*)&smem[0][wm * 64 + t * 16 + r16][s * 32 + q * 8];
                bf[t] = *(half8v*)&smem[1][wn * 64 + t * 16 + r16][s * 32 + q * 8];
            }
#pragma unroll
            for (int mt = 0; mt < 4; ++mt)
#pragma unroll
                for (int nt = 0; nt < 4; ++nt)
                    acc[mt][nt] = __builtin_amdgcn_mfma_f32_16x16x32_f16(
                        af[mt], bf[nt], acc[mt][nt], 0, 0, 0);
        }
        __syncthreads();
    }
    // epilogue: repack C to fp16 via LDS (C layout: row=q*4+reg, col=r16)
    _Float16 (*eb)[136] = (_Float16(*)[136]) & smem[0][0][0];
#pragma unroll
    for (int mt = 0; mt < 4; ++mt) {
        const int er = wm * 64 + mt * 16 + q * 4;
#pragma unroll
        for (int reg = 0; reg < 4; ++reg)
#pragma unroll
            for (int nt = 0; nt < 4; ++nt)
                eb[er + reg][wn * 64 + nt * 16 + r16] = (_Float16)acc[mt][nt][reg];
    }
    __syncthreads();
    const int r = tid >> 1, hh = tid & 1;
    const int grow = row0 + r;
    if (grow < n) {
        float ds = 0.f, dd = 0.f;
#pragma unroll
        for (int i = 0; i < 8; ++i) {
            half8v v = *(half8v*)&eb[r][hh * 64 + i * 8];
            *(half8v*)(h16 + (size_t)grow * HCH + hh * 64 + i * 8) = v;
#pragma unroll
            for (int j = 0; j < 8; ++j) {
                float f = (float)v[j];
                ds = fmaf(f, attv[0][hh * 64 + i * 8 + j], ds);
                dd = fmaf(f, attv[1][hh * 64 + i * 8 + j], dd);
            }
        }
        a_s[2 * grow + hh] = ds;
        a_d[2 * grow + hh] = dd;
    }
}

// ---------------- bucket edges by dst region ----------------
__global__ __launch_bounds__(256) void bucket_kernel(const int* __restrict__ src,
                                                     const int* __restrict__ dst,
                                                     int* __restrict__ gcursor,
                                                     int* __restrict__ bstore, int e)
{
    __shared__ int hist[NB];
    __shared__ int base[NB];
    const int tid = threadIdx.x;
    const int per = (e + gridDim.x - 1) / gridDim.x;
    const int e0 = blockIdx.x * per;
    const int e1 = min(e, e0 + per);
    for (int i = tid; i < NB; i += 256) hist[i] = 0;
    __syncthreads();
    for (int i = e0 + tid; i < e1; i += 256)
        atomicAdd(&hist[dst[i] / NPB], 1);
    __syncthreads();
    for (int b = tid; b < NB; b += 256) {
        int c = hist[b];
        base[b] = c ? atomicAdd(&gcursor[b], c) : 0;
        hist[b] = 0;
    }
    __syncthreads();
    for (int i = e0 + tid; i < e1; i += 256) {
        int d = dst[i];
        int s = src[i];
        int b = d / NPB;
        int pos = base[b] + atomicAdd(&hist[b], 1);
        if (pos >= 0 && pos < CAP) bstore[b * CAP + pos] = (s << 7) | (d - b * NPB);
    }
}

// ---------------- per-bucket LDS counting sort (in place) -------------------
// bstore[b*CAP .. b*CAP+cnt) is rewritten sorted-by-local-dst; gstart/gend set
__global__ __launch_bounds__(256) void sort_kernel(
    const int* __restrict__ gcursor, int* __restrict__ bstore,
    int* __restrict__ gstart, int* __restrict__ gend, int n)
{
    __shared__ int raw[CAP];
    __shared__ int sorted[CAP];
    __shared__ int curs[128];
    __shared__ int scanbuf[128];
    const int tid = threadIdx.x;
    const int b = blockIdx.x;
    const int node0 = b * NPB;
    const int nnode = min(NPB, n - node0);
    if (nnode <= 0) return;
    int cnt = gcursor[b];
    cnt = cnt < 0 ? 0 : (cnt > CAP ? CAP : cnt);

    for (int i = tid; i < cnt; i += 256) raw[i] = bstore[b * CAP + i];
    if (tid < 128) curs[tid] = 0;
    __syncthreads();
    for (int i = tid; i < cnt; i += 256) atomicAdd(&curs[raw[i] & 127], 1);
    __syncthreads();
    if (tid < 128) scanbuf[tid] = curs[tid];
    __syncthreads();
    for (int off = 1; off < 128; off <<= 1) {
        int v = 0;
        if (tid < 128) { v = scanbuf[tid]; if (tid >= off) v += scanbuf[tid - off]; }
        __syncthreads();
        if (tid < 128) scanbuf[tid] = v;
        __syncthreads();
    }
    if (tid < 128) {
        int ex = tid ? scanbuf[tid - 1] : 0;
        curs[tid] = ex;
        if (tid < nnode) {
            gstart[node0 + tid] = b * CAP + ex;
            gend[node0 + tid] = b * CAP + scanbuf[tid];
        }
    }
    __syncthreads();
    for (int i = tid; i < cnt; i += 256) {
        int item = raw[i];
        int pos = atomicAdd(&curs[item & 127], 1);
        if (pos >= 0 && pos < CAP) sorted[pos] = item >> 7;
    }
    __syncthreads();
    for (int i = tid; i < cnt; i += 256) bstore[b * CAP + i] = sorted[i];
}

// ---------------- per-node softmax aggregation (fp16 gather) ----------------
// wave per dst node; cooperative 64-edge chunks staged in wave-private LDS
__global__ __launch_bounds__(256) void agg_kernel(
    const _Float16* __restrict__ h16, const float2* __restrict__ a_s,
    const float2* __restrict__ a_d, const int* __restrict__ gstart,
    const int* __restrict__ gend, const int* __restrict__ ssort,
    const float* __restrict__ bias, _Float16* __restrict__ xc16, int n)
{
    __shared__ float4 sh[4][64];
    const int wid = threadIdx.x >> 6, lane = threadIdx.x & 63;
    const int node = blockIdx.x * 4 + wid;
    const bool valid = node < n;
    const int nn = valid ? node : 0;
    int start = gstart[nn], end = gend[nn];
    // poison guards (never triggered in correct operation)
    start = start < 0 ? 0 : (start > NB * CAP ? NB * CAP : start);
    end = end < start ? start : (end > NB * CAP ? NB * CAP : end);
    const float2 ad = a_d[nn];
    const float2 asn = a_s[nn];

    float acc0 = 0.f, acc1 = 0.f;
    float s0 = 0.f, s1 = 0.f;

    for (int base = start; base < end; base += 64) {
        const int j = base + lane;
        const int cnt = min(64, end - base);
        float p0 = 0.f, p1 = 0.f;
        int s = 0;
        if (j < end) {
            s = ssort[j];
            if ((unsigned)s >= (unsigned)n) s = 0;   // poison guard
            float2 a = a_s[s];
            p0 = __expf(lrelu(a.x + ad.x));
            p1 = __expf(lrelu(a.y + ad.y));
        }
        s0 += p0;
        s1 += p1;
        sh[wid][lane] = make_float4(__int_as_float(s), p0, p1, 0.f);
        __builtin_amdgcn_wave_barrier();
        for (int t = 0; t < cnt; ++t) {
            const float4 e = sh[wid][t];
            const half2v hv =
                *(const half2v*)(h16 + (size_t)__float_as_int(e.x) * HCH + 2 * lane);
            const float pl = (lane < 32) ? e.y : e.z;
            acc0 = fmaf(pl, (float)hv[0], acc0);
            acc1 = fmaf(pl, (float)hv[1], acc1);
        }
        __builtin_amdgcn_wave_barrier();
    }
    // self loop
    {
        const float ps0 = __expf(lrelu(asn.x + ad.x));
        const float ps1 = __expf(lrelu(asn.y + ad.y));
        const half2v hv = *(const half2v*)(h16 + (size_t)nn * HCH + 2 * lane);
        const float pl = (lane < 32) ? ps0 : ps1;
        acc0 = fmaf(pl, (float)hv[0], acc0);
        acc1 = fmaf(pl, (float)hv[1], acc1);
        if (lane == 0) { s0 += ps0; s1 += ps1; }
    }
#pragma unroll
    for (int m = 32; m >= 1; m >>= 1) {
        s0 += __shfl_xor(s0, m, 64);
        s1 += __shfl_xor(s1, m, 64);
    }
    const float dl = (lane < 32) ? s0 : s1;
    if (valid) {
        const float o0 = fmaxf(acc0 / dl + bias[2 * lane], 0.f);
        const float o1 = fmaxf(acc1 / dl + bias[2 * lane + 1], 0.f);
        half2v o = { (_Float16)o0, (_Float16)o1 };
        *(half2v*)(xc16 + (size_t)node * HCH + 2 * lane) = o;
    }
}

// ---------------- FC half: out (+)= xc16[N,128] @ fcW_half[128,64] (+ fcb) --
__global__ __launch_bounds__(256) void fc_kernel(const _Float16* __restrict__ xc16,
                                                 const float* __restrict__ fw,
                                                 const float* __restrict__ fcb,
                                                 float* __restrict__ out, int n, int beta)
{
    __shared__ float xcs[32][132];
    __shared__ float fws[32][64];
    const int tid = threadIdx.x;
    const int tx = tid & 15;
    const int ty = tid >> 4;
    const int row0 = blockIdx.x * 128;

    float acc[8][4];
#pragma unroll
    for (int i = 0; i < 8; ++i)
#pragma unroll
        for (int j = 0; j < 4; ++j) acc[i][j] = 0.f;

    for (int kt = 0; kt < HCH; kt += 32) {
#pragma unroll
        for (int i = 0; i < 2; ++i) {
            const int idx = i * 256 + tid;
            const int row = idx >> 2;
            const int cg = (idx & 3) * 8;
            half8v v = { 0, 0, 0, 0, 0, 0, 0, 0 };
            if (row0 + row < n)
                v = *(const half8v*)(xc16 + (size_t)(row0 + row) * HCH + kt + cg);
#pragma unroll
            for (int j = 0; j < 8; ++j) xcs[cg + j][row] = (float)v[j];
        }
#pragma unroll
        for (int r = 0; r < 2; ++r) {
            const int idx = r * 256 + tid;
            const int k = idx >> 4;
            const int c = (idx & 15) * 4;
            *(float4*)&fws[k][c] = *(const float4*)(fw + (size_t)(kt + k) * OUT_DIM + c);
        }
        __syncthreads();
#pragma unroll
        for (int k = 0; k < 32; ++k) {
            const float4 a0 = *(float4*)&xcs[k][ty * 8];
            const float4 a1 = *(float4*)&xcs[k][ty * 8 + 4];
            const float4 bq = *(float4*)&fws[k][tx * 4];
            const float av[8] = { a0.x, a0.y, a0.z, a0.w, a1.x, a1.y, a1.z, a1.w };
            const float bv[4] = { bq.x, bq.y, bq.z, bq.w };
#pragma unroll
            for (int i = 0; i < 8; ++i)
#pragma unroll
                for (int j = 0; j < 4; ++j)
                    acc[i][j] = fmaf(av[i], bv[j], acc[i][j]);
        }
        __syncthreads();
    }
    const float4 bb = *(const float4*)(fcb + tx * 4);
#pragma unroll
    for (int i = 0; i < 8; ++i) {
        const int row = row0 + ty * 8 + i;
        if (row < n) {
            float4 v = make_float4(acc[i][0], acc[i][1], acc[i][2], acc[i][3]);
            if (beta) {
                const float4 o = *(const float4*)(out + (size_t)row * OUT_DIM + tx * 4);
                v.x += o.x; v.y += o.y; v.z += o.z; v.w += o.w;
            } else {
                v.x += bb.x; v.y += bb.y; v.z += bb.z; v.w += bb.w;
            }
            *(float4*)(out + (size_t)row * OUT_DIM + tx * 4) = v;
        }
    }
}

// ---------------- launch ----------------
extern "C" void kernel_launch(void* const* d_in, const int* in_sizes, int n_in,
                              void* d_out, int out_size, void* d_ws, size_t ws_size,
                              hipStream_t stream)
{
    const float* x = (const float*)d_in[0];
    const int* ei[2] = { (const int*)d_in[1], (const int*)d_in[2] };
    const float* W[2] = { (const float*)d_in[3], (const float*)d_in[7] };
    const float* attS[2] = { (const float*)d_in[4], (const float*)d_in[8] };
    const float* attD[2] = { (const float*)d_in[5], (const float*)d_in[9] };
    const float* bias[2] = { (const float*)d_in[6], (const float*)d_in[10] };
    const float* fcW = (const float*)d_in[11];
    const float* fcb = (const float*)d_in[12];
    float* out = (float*)d_out;

    char* p = (char*)d_ws;
    size_t need = 0;
    auto carve = [&](size_t bytes) {
        char* r = p;
        size_t b = (bytes + 255) & ~(size_t)255;
        p += b;
        need += b;
        return r;
    };
    _Float16* h16 = (_Float16*)carve((size_t)NN * HCH * 2);
    _Float16* xc16 = (_Float16*)carve((size_t)NN * HCH * 2);
    _Float16* wt = (_Float16*)carve((size_t)2 * IN_DIM * HCH * 2);
    float* a_s = (float*)carve((size_t)NN * 8);
    float* a_d = (float*)carve((size_t)NN * 8);
    int* gcursor = (int*)carve((size_t)NB * 4);
    int* bstore = (int*)carve((size_t)NB * CAP * 4);
    int* gstart = (int*)carve((size_t)NN * 4);
    int* gend = (int*)carve((size_t)NN * 4);
    if (need > ws_size) return;  // loud correctness failure instead of OOB crash

    const int gemm_blocks = (NN + 127) / 128;   // 782
    const int node_blocks = (NN + 3) / 4;       // 25000

    convw_kernel<<<(2 * IN_DIM * HCH + 255) / 256, 256, 0, stream>>>(W[0], W[1], wt);

    for (int layer = 0; layer < 2; ++layer) {
        gemm_mfma<<<gemm_blocks, 256, 0, stream>>>(x, wt + (size_t)layer * IN_DIM * HCH,
                                                   attS[layer], attD[layer],
                                                   h16, a_s, a_d, NN);
        hipMemsetAsync(gcursor, 0, (size_t)NB * 4, stream);
        bucket_kernel<<<256, 256, 0, stream>>>(ei[layer], ei[layer] + EE, gcursor, bstore, EE);
        sort_kernel<<<NB, 256, 0, stream>>>(gcursor, bstore, gstart, gend, NN);
        agg_kernel<<<node_blocks, 256, 0, stream>>>(h16, (const float2*)a_s, (const float2*)a_d,
                                                    gstart, gend, bstore, bias[layer],
                                                    xc16, NN);
        fc_kernel<<<gemm_blocks, 256, 0, stream>>>(xc16, fcW + (size_t)layer * HCH * OUT_DIM,
                                                   fcb, out, NN, layer);
    }
}

// Round 7
// 532.434 us; speedup vs baseline: 2.4323x; 1.1355x over previous
//
#include <hip/hip_runtime.h>
#include <hip/hip_fp16.h>
#include <math.h>

#define NN 100000
#define IN_DIM 256
#define HCH 128      // HEADS*HID
#define OUT_DIM 64
#define EE 1600000
#define NEG_SLOPE 0.2f

#define NB 1024      // dst buckets
#define NPB 98       // nodes per bucket (1024*98 >= 100000)
#define CAP 2048     // bucket capacity (mean 1562, std ~40 -> 12 sigma margin)

typedef _Float16 half8v __attribute__((ext_vector_type(8)));
typedef _Float16 half4v __attribute__((ext_vector_type(4)));
typedef _Float16 half2v __attribute__((ext_vector_type(2)));
typedef float float4v __attribute__((ext_vector_type(4)));

__device__ __forceinline__ float lrelu(float v) { return v > 0.f ? v : NEG_SLOPE * v; }

// ---- convert: wt[l][col][k] = W_l[k][col] fp16 ; fcw16[l][col][k] = fcW[l*128+k][col]
__global__ void convw_kernel(const float* __restrict__ W0, const float* __restrict__ W1,
                             const float* __restrict__ fcW,
                             _Float16* __restrict__ wt, _Float16* __restrict__ fcw16)
{
    int i = blockIdx.x * 256 + threadIdx.x;
    if (i < 2 * IN_DIM * HCH) {
        int l = i >> 15, rem = i & 32767;
        int c = rem >> 8, k = rem & 255;
        const float* W = l ? W1 : W0;
        wt[i] = (_Float16)W[(size_t)k * HCH + c];
        return;
    }
    int j = i - 2 * IN_DIM * HCH;
    if (j < 2 * HCH * OUT_DIM) {
        int l = j >> 13, rem = j & 8191;
        int c = rem >> 7, k = rem & 127;
        fcw16[j] = (_Float16)fcW[(size_t)(l * HCH + k) * OUT_DIM + c];
    }
}

// ---------------- fused GEMM (fp16 MFMA) + attention-score epilogue --------
// 64-row tiles, 1563 blocks (~6 rounds/CU), 4 waves as 2x2, wave tile 32x64
__global__ __launch_bounds__(256, 5) void gemm_mfma(
    const float* __restrict__ x, const _Float16* __restrict__ wt,
    const float* __restrict__ att_src, const float* __restrict__ att_dst,
    _Float16* __restrict__ h16, float* __restrict__ a_s, float* __restrict__ a_d, int n)
{
    __shared__ _Float16 smem[64 * 72 + 128 * 72];   // A[64][72] then B[128][72]
    __shared__ float attv[2][128];
    _Float16 (*As)[72] = (_Float16(*)[72])smem;
    _Float16 (*Bs)[72] = (_Float16(*)[72])(smem + 64 * 72);
    const int tid = threadIdx.x;
    const int lane = tid & 63, wave = tid >> 6;
    const int wm = wave & 1, wn = wave >> 1;
    const int q = lane >> 4, r16 = lane & 15;
    const int row0 = blockIdx.x * 64;

    if (tid < 128) { attv[0][tid] = att_src[tid]; attv[1][tid] = att_dst[tid]; }

    float4v acc[2][4];
#pragma unroll
    for (int i = 0; i < 2; ++i)
#pragma unroll
        for (int j = 0; j < 4; ++j) acc[i][j] = (float4v){0.f, 0.f, 0.f, 0.f};

    const int ar = tid >> 2, aq = tid & 3;   // A: row, k-quarter (16 floats)
    const int br = tid >> 1, bh = tid & 1;   // B: col, k-half (32 halves)
    const bool rok = (row0 + ar) < n;
    for (int kt = 0; kt < IN_DIM; kt += 64) {
        const float* xp = x + (size_t)(row0 + ar) * IN_DIM + kt + aq * 16;
#pragma unroll
        for (int i = 0; i < 4; ++i) {
            float4 v = rok ? *(const float4*)(xp + i * 4) : make_float4(0.f, 0.f, 0.f, 0.f);
            half4v hv = { (_Float16)v.x, (_Float16)v.y, (_Float16)v.z, (_Float16)v.w };
            *(half4v*)&As[ar][aq * 16 + i * 4] = hv;
        }
        const _Float16* wp = wt + (size_t)br * IN_DIM + kt + bh * 32;
#pragma unroll
        for (int i = 0; i < 4; ++i)
            *(half8v*)&Bs[br][bh * 32 + i * 8] = *(const half8v*)(wp + i * 8);
        __syncthreads();
#pragma unroll
        for (int s = 0; s < 2; ++s) {
            half8v af[2], bf[4];
#pragma unroll
            for (int t = 0; t < 2; ++t)
                af[t] = *(half8v*)&As[wm * 32 + t * 16 + r16][s * 32 + q * 8];
#pragma unroll
            for (int t = 0; t < 4; ++t)
                bf[t] = *(half8v*)&Bs[wn * 64 + t * 16 + r16][s * 32 + q * 8];
#pragma unroll
            for (int mt = 0; mt < 2; ++mt)
#pragma unroll
                for (int nt = 0; nt < 4; ++nt)
                    acc[mt][nt] = __builtin_amdgcn_mfma_f32_16x16x32_f16(
                        af[mt], bf[nt], acc[mt][nt], 0, 0, 0);
        }
        __syncthreads();
    }
    // epilogue: repack C to fp16 via LDS (C layout: row=q*4+reg, col=r16)
    _Float16 (*eb)[136] = (_Float16(*)[136])smem;   // 64x136 = 17.4 KB fits
#pragma unroll
    for (int mt = 0; mt < 2; ++mt) {
        const int er = wm * 32 + mt * 16 + q * 4;
#pragma unroll
        for (int reg = 0; reg < 4; ++reg)
#pragma unroll
            for (int nt = 0; nt < 4; ++nt)
                eb[er + reg][wn * 64 + nt * 16 + r16] = (_Float16)acc[mt][nt][reg];
    }
    __syncthreads();
    const int r = tid >> 1, hh = tid & 1;
    if (r < 64) {
        const int grow = row0 + r;
        if (grow < n) {
            float ds = 0.f, dd = 0.f;
#pragma unroll
            for (int i = 0; i < 8; ++i) {
                half8v v = *(half8v*)&eb[r][hh * 64 + i * 8];
                *(half8v*)(h16 + (size_t)grow * HCH + hh * 64 + i * 8) = v;
#pragma unroll
                for (int j = 0; j < 8; ++j) {
                    float f = (float)v[j];
                    ds = fmaf(f, attv[0][hh * 64 + i * 8 + j], ds);
                    dd = fmaf(f, attv[1][hh * 64 + i * 8 + j], dd);
                }
            }
            a_s[2 * grow + hh] = ds;
            a_d[2 * grow + hh] = dd;
        }
    }
}

// ---------------- bucket edges by dst region (1024 thr for TLP) -------------
__global__ __launch_bounds__(1024) void bucket_kernel(const int* __restrict__ src,
                                                      const int* __restrict__ dst,
                                                      int* __restrict__ gcursor,
                                                      int* __restrict__ bstore, int e)
{
    __shared__ int hist[NB];
    __shared__ int base[NB];
    const int tid = threadIdx.x;
    const int per = (e + gridDim.x - 1) / gridDim.x;
    const int e0 = blockIdx.x * per;
    const int e1 = min(e, e0 + per);
    for (int i = tid; i < NB; i += 1024) hist[i] = 0;
    __syncthreads();
    for (int i = e0 + tid; i < e1; i += 1024)
        atomicAdd(&hist[dst[i] / NPB], 1);
    __syncthreads();
    for (int b = tid; b < NB; b += 1024) {
        int c = hist[b];
        base[b] = c ? atomicAdd(&gcursor[b], c) : 0;
        hist[b] = 0;
    }
    __syncthreads();
    for (int i = e0 + tid; i < e1; i += 1024) {
        int d = dst[i];
        int s = src[i];
        int b = d / NPB;
        int pos = base[b] + atomicAdd(&hist[b], 1);
        if (pos >= 0 && pos < CAP) bstore[b * CAP + pos] = (s << 7) | (d - b * NPB);
    }
}

// ---------------- per-bucket LDS counting sort (in place) -------------------
__global__ __launch_bounds__(256) void sort_kernel(
    const int* __restrict__ gcursor, int* __restrict__ bstore,
    int* __restrict__ gstart, int* __restrict__ gend, int n)
{
    __shared__ int raw[CAP];
    __shared__ int sorted[CAP];
    __shared__ int curs[128];
    __shared__ int scanbuf[128];
    const int tid = threadIdx.x;
    const int b = blockIdx.x;
    const int node0 = b * NPB;
    const int nnode = min(NPB, n - node0);
    if (nnode <= 0) return;
    int cnt = gcursor[b];
    cnt = cnt < 0 ? 0 : (cnt > CAP ? CAP : cnt);

    for (int i = tid; i < cnt; i += 256) raw[i] = bstore[b * CAP + i];
    if (tid < 128) curs[tid] = 0;
    __syncthreads();
    for (int i = tid; i < cnt; i += 256) atomicAdd(&curs[raw[i] & 127], 1);
    __syncthreads();
    if (tid < 128) scanbuf[tid] = curs[tid];
    __syncthreads();
    for (int off = 1; off < 128; off <<= 1) {
        int v = 0;
        if (tid < 128) { v = scanbuf[tid]; if (tid >= off) v += scanbuf[tid - off]; }
        __syncthreads();
        if (tid < 128) scanbuf[tid] = v;
        __syncthreads();
    }
    if (tid < 128) {
        int ex = tid ? scanbuf[tid - 1] : 0;
        curs[tid] = ex;
        if (tid < nnode) {
            gstart[node0 + tid] = b * CAP + ex;
            gend[node0 + tid] = b * CAP + scanbuf[tid];
        }
    }
    __syncthreads();
    for (int i = tid; i < cnt; i += 256) {
        int item = raw[i];
        int pos = atomicAdd(&curs[item & 127], 1);
        if (pos >= 0 && pos < CAP) sorted[pos] = item >> 7;
    }
    __syncthreads();
    for (int i = tid; i < cnt; i += 256) bstore[b * CAP + i] = sorted[i];
}

// ---------------- per-node softmax aggregation (fp16 gather) ----------------
// 6250 blocks; each wave serially handles 4 consecutive nodes
__global__ __launch_bounds__(256) void agg_kernel(
    const _Float16* __restrict__ h16, const float2* __restrict__ a_s,
    const float2* __restrict__ a_d, const int* __restrict__ gstart,
    const int* __restrict__ gend, const int* __restrict__ ssort,
    const float* __restrict__ bias, _Float16* __restrict__ xc16, int n)
{
    __shared__ float2 sh[4][2][64];   // [wave][head-half][slot]: (src_bits, p)
    const int wid = threadIdx.x >> 6, lane = threadIdx.x & 63;
    const int wbase = (blockIdx.x * 4 + wid) * 4;
    const float2* myhalf = &sh[wid][lane >> 5][0];
    const float b0 = bias[2 * lane], b1 = bias[2 * lane + 1];

    for (int ni = 0; ni < 4; ++ni) {
        const int node = wbase + ni;
        const bool valid = node < n;
        const int nn = valid ? node : 0;
        int start = gstart[nn], end = gend[nn];
        start = start < 0 ? 0 : (start > NB * CAP ? NB * CAP : start);
        end = end < start ? start : (end > NB * CAP ? NB * CAP : end);
        const float2 ad = a_d[nn];
        const float2 asn = a_s[nn];

        float acc0 = 0.f, acc1 = 0.f;
        float s0 = 0.f, s1 = 0.f;

        for (int base = start; base < end; base += 64) {
            const int j = base + lane;
            const int cnt = min(64, end - base);
            float p0 = 0.f, p1 = 0.f;
            int s = 0;
            if (j < end) {
                s = ssort[j];
                if ((unsigned)s >= (unsigned)n) s = 0;   // poison guard
                float2 a = a_s[s];
                p0 = __expf(lrelu(a.x + ad.x));
                p1 = __expf(lrelu(a.y + ad.y));
            }
            s0 += p0;
            s1 += p1;
            sh[wid][0][lane] = make_float2(__int_as_float(s), p0);
            sh[wid][1][lane] = make_float2(__int_as_float(s), p1);
            __builtin_amdgcn_wave_barrier();
            int t = 0;
            for (; t + 2 <= cnt; t += 2) {
                const float2 e0 = myhalf[t];
                const float2 e1 = myhalf[t + 1];
                const half2v hv0 =
                    *(const half2v*)(h16 + (size_t)__float_as_int(e0.x) * HCH + 2 * lane);
                const half2v hv1 =
                    *(const half2v*)(h16 + (size_t)__float_as_int(e1.x) * HCH + 2 * lane);
                acc0 = fmaf(e0.y, (float)hv0[0], acc0);
                acc1 = fmaf(e0.y, (float)hv0[1], acc1);
                acc0 = fmaf(e1.y, (float)hv1[0], acc0);
                acc1 = fmaf(e1.y, (float)hv1[1], acc1);
            }
            if (t < cnt) {
                const float2 e0 = myhalf[t];
                const half2v hv0 =
                    *(const half2v*)(h16 + (size_t)__float_as_int(e0.x) * HCH + 2 * lane);
                acc0 = fmaf(e0.y, (float)hv0[0], acc0);
                acc1 = fmaf(e0.y, (float)hv0[1], acc1);
            }
            __builtin_amdgcn_wave_barrier();
        }
        // self loop
        {
            const float ps0 = __expf(lrelu(asn.x + ad.x));
            const float ps1 = __expf(lrelu(asn.y + ad.y));
            const half2v hv = *(const half2v*)(h16 + (size_t)nn * HCH + 2 * lane);
            const float pl = (lane < 32) ? ps0 : ps1;
            acc0 = fmaf(pl, (float)hv[0], acc0);
            acc1 = fmaf(pl, (float)hv[1], acc1);
            if (lane == 0) { s0 += ps0; s1 += ps1; }
        }
#pragma unroll
        for (int m = 32; m >= 1; m >>= 1) {
            s0 += __shfl_xor(s0, m, 64);
            s1 += __shfl_xor(s1, m, 64);
        }
        const float dl = (lane < 32) ? s0 : s1;
        if (valid) {
            const float o0 = fmaxf(acc0 / dl + b0, 0.f);
            const float o1 = fmaxf(acc1 / dl + b1, 0.f);
            half2v o = { (_Float16)o0, (_Float16)o1 };
            *(half2v*)(xc16 + (size_t)node * HCH + 2 * lane) = o;
        }
    }
}

// ---------------- FC half via MFMA: out (+)= xc16 @ fcW_half + fcb ----------
// 64-row tiles, wave w handles rows w*16..w*16+15; B direct from global (L1-hot)
__global__ __launch_bounds__(256) void fc_mfma(const _Float16* __restrict__ xc16,
                                               const _Float16* __restrict__ fw16,
                                               const float* __restrict__ fcb,
                                               float* __restrict__ out, int n, int beta)
{
    __shared__ _Float16 axs[64][136];
    const int tid = threadIdx.x;
    const int lane = tid & 63, wave = tid >> 6;
    const int q = lane >> 4, r16 = lane & 15;
    const int row0 = blockIdx.x * 64;

    // stage A: 64 rows x 128 k (4 half8 loads/thread, coalesced)
#pragma unroll
    for (int i = 0; i < 4; ++i) {
        const int idx = i * 256 + tid;
        const int row = idx >> 4;
        const int kg = (idx & 15) * 8;
        half8v v = { 0, 0, 0, 0, 0, 0, 0, 0 };
        if (row0 + row < n)
            v = *(const half8v*)(xc16 + (size_t)(row0 + row) * HCH + kg);
        *(half8v*)&axs[row][kg] = v;
    }
    __syncthreads();

    float4v acc[4];
#pragma unroll
    for (int i = 0; i < 4; ++i) acc[i] = (float4v){0.f, 0.f, 0.f, 0.f};
#pragma unroll
    for (int s = 0; s < 4; ++s) {
        const half8v af = *(half8v*)&axs[wave * 16 + r16][s * 32 + q * 8];
#pragma unroll
        for (int nt = 0; nt < 4; ++nt) {
            const half8v bf =
                *(const half8v*)(fw16 + (size_t)(nt * 16 + r16) * HCH + s * 32 + q * 8);
            acc[nt] = __builtin_amdgcn_mfma_f32_16x16x32_f16(af, bf, acc[nt], 0, 0, 0);
        }
    }
#pragma unroll
    for (int nt = 0; nt < 4; ++nt) {
        const int col = nt * 16 + r16;
#pragma unroll
        for (int reg = 0; reg < 4; ++reg) {
            const int row = row0 + wave * 16 + q * 4 + reg;
            if (row < n) {
                float v = acc[nt][reg];
                if (beta) v += out[(size_t)row * OUT_DIM + col];
                else v += fcb[col];
                out[(size_t)row * OUT_DIM + col] = v;
            }
        }
    }
}

// ---------------- launch ----------------
extern "C" void kernel_launch(void* const* d_in, const int* in_sizes, int n_in,
                              void* d_out, int out_size, void* d_ws, size_t ws_size,
                              hipStream_t stream)
{
    const float* x = (const float*)d_in[0];
    const int* ei[2] = { (const int*)d_in[1], (const int*)d_in[2] };
    const float* W[2] = { (const float*)d_in[3], (const float*)d_in[7] };
    const float* attS[2] = { (const float*)d_in[4], (const float*)d_in[8] };
    const float* attD[2] = { (const float*)d_in[5], (const float*)d_in[9] };
    const float* bias[2] = { (const float*)d_in[6], (const float*)d_in[10] };
    const float* fcW = (const float*)d_in[11];
    const float* fcb = (const float*)d_in[12];
    float* out = (float*)d_out;

    char* p = (char*)d_ws;
    size_t need = 0;
    auto carve = [&](size_t bytes) {
        char* r = p;
        size_t b = (bytes + 255) & ~(size_t)255;
        p += b;
        need += b;
        return r;
    };
    _Float16* h16 = (_Float16*)carve((size_t)NN * HCH * 2);
    _Float16* xc16 = (_Float16*)carve((size_t)NN * HCH * 2);
    _Float16* wt = (_Float16*)carve((size_t)2 * IN_DIM * HCH * 2);
    _Float16* fcw16 = (_Float16*)carve((size_t)2 * HCH * OUT_DIM * 2);
    float* a_s = (float*)carve((size_t)NN * 8);
    float* a_d = (float*)carve((size_t)NN * 8);
    int* gcursor = (int*)carve((size_t)NB * 4);
    int* bstore = (int*)carve((size_t)NB * CAP * 4);
    int* gstart = (int*)carve((size_t)NN * 4);
    int* gend = (int*)carve((size_t)NN * 4);
    if (need > ws_size) return;  // loud correctness failure instead of OOB crash

    const int gemm_blocks = (NN + 63) / 64;     // 1563
    const int agg_blocks = (NN + 15) / 16;      // 6250
    const int conv_total = 2 * IN_DIM * HCH + 2 * HCH * OUT_DIM;

    convw_kernel<<<(conv_total + 255) / 256, 256, 0, stream>>>(W[0], W[1], fcW, wt, fcw16);

    for (int layer = 0; layer < 2; ++layer) {
        gemm_mfma<<<gemm_blocks, 256, 0, stream>>>(x, wt + (size_t)layer * IN_DIM * HCH,
                                                   attS[layer], attD[layer],
                                                   h16, a_s, a_d, NN);
        hipMemsetAsync(gcursor, 0, (size_t)NB * 4, stream);
        bucket_kernel<<<256, 1024, 0, stream>>>(ei[layer], ei[layer] + EE, gcursor, bstore, EE);
        sort_kernel<<<NB, 256, 0, stream>>>(gcursor, bstore, gstart, gend, NN);
        agg_kernel<<<agg_blocks, 256, 0, stream>>>(h16, (const float2*)a_s, (const float2*)a_d,
                                                   gstart, gend, bstore, bias[layer],
                                                   xc16, NN);
        fc_mfma<<<gemm_blocks, 256, 0, stream>>>(xc16, fcw16 + (size_t)layer * HCH * OUT_DIM,
                                                 fcb, out, NN, layer);
    }
}